// Round 1
// baseline (1544.167 us; speedup 1.0000x reference)
//
#include <hip/hip_runtime.h>
#include <hip/hip_bf16.h>

using u16 = unsigned short;
using u32 = unsigned int;

typedef __attribute__((ext_vector_type(8))) short short8;
typedef __attribute__((ext_vector_type(4))) float f32x4;

__device__ __forceinline__ u16 f2bf_u16(float f) {
    __hip_bfloat16 h = __float2bfloat16(f);
    return __builtin_bit_cast(u16, h);
}
__device__ __forceinline__ float bfu(u32 u) { return __uint_as_float(u << 16); }

static constexpr int NN = 50000;
static constexpr int NE = 1600000;
static constexpr int NIDX = 8192;

// ---------------- graph preprocessing ----------------

__global__ void hist_kernel(const int* __restrict__ src, const int* __restrict__ dst,
                            int* deg_out, int* deg_in, int E) {
    int e = blockIdx.x * blockDim.x + threadIdx.x;
    if (e < E) {
        atomicAdd(&deg_out[src[e]], 1);
        atomicAdd(&deg_in[dst[e]], 1);
    }
}

__global__ void norm_kernel(const int* __restrict__ deg_out, const int* __restrict__ deg_in,
                            float* ns, float* nd, int n) {
    int i = blockIdx.x * blockDim.x + threadIdx.x;
    if (i < n) {
        ns[i] = rsqrtf(fmaxf((float)deg_out[i], 1.f));
        nd[i] = rsqrtf(fmaxf((float)deg_in[i], 1.f));
    }
}

__global__ __launch_bounds__(1024)
void scan_kernel(const int* __restrict__ deg, int* row_ptr, int* cursor, int n) {
    __shared__ int wsum[16];
    __shared__ int carry;
    int t = threadIdx.x;
    int lane = t & 63, wid = t >> 6;
    if (t == 0) carry = 0;
    __syncthreads();
    for (int base = 0; base < n; base += 1024) {
        int i = base + t;
        int v = (i < n) ? deg[i] : 0;
        int x = v;
        #pragma unroll
        for (int d = 1; d < 64; d <<= 1) {
            int y = __shfl_up(x, d, 64);
            if (lane >= d) x += y;
        }
        if (lane == 63) wsum[wid] = x;
        __syncthreads();
        if (t == 0) {
            int run = carry;
            #pragma unroll
            for (int w = 0; w < 16; ++w) { int s = wsum[w]; wsum[w] = run; run += s; }
            carry = run;
        }
        __syncthreads();
        if (i < n) {
            int excl = wsum[wid] + x - v;
            row_ptr[i] = excl;
            cursor[i] = excl;
        }
        __syncthreads();
    }
    if (t == 0) row_ptr[n] = carry;
}

__global__ void scatter_kernel(const int* __restrict__ src, const int* __restrict__ dst,
                               int* cursor, int* csr_src, int E) {
    int e = blockIdx.x * blockDim.x + threadIdx.x;
    if (e < E) {
        int pos = atomicAdd(&cursor[dst[e]], 1);
        csr_src[pos] = src[e];
    }
}

// W [K][N] f32  ->  Wt [N][K] bf16
__global__ void convw_kernel(const float* __restrict__ W, u16* Wt, int K, int N) {
    int idx = blockIdx.x * blockDim.x + threadIdx.x;
    if (idx < K * N) {
        int k = idx / N, n = idx - k * N;
        Wt[(size_t)n * K + k] = f2bf_u16(W[idx]);
    }
}

// ---------------- MFMA GEMM: C = A @ Bt^T ----------------
// A: [M][K] (f32 or bf16), Bt: [N][K] bf16, C: [M][N] (bf16 or f32)
// TRIANG: A==Bt==R, write zeros for col<row, zero-fill blocks below diagonal.

template<bool A_F32, bool OUT_BF16, bool TRIANG>
__global__ __launch_bounds__(256)
void gemm_kernel(const void* __restrict__ A_, const u16* __restrict__ Bt,
                 void* __restrict__ C_, int M, int N, int K) {
    int it = blockIdx.x, jt = blockIdx.y;
    int t = threadIdx.x;
    int brow = it * 128, bcol = jt * 128;
    float* Cf = (float*)C_;
    if (TRIANG && jt < it) {
        #pragma unroll
        for (int p = 0; p < 16; ++p) {
            int idx = p * 256 + t;
            int r = idx >> 5, c4 = idx & 31;
            *(float4*)(Cf + (size_t)(brow + r) * N + bcol + c4 * 4) = make_float4(0.f, 0.f, 0.f, 0.f);
        }
        return;
    }
    __shared__ u16 As[128 * 40];
    __shared__ u16 Bs[128 * 40];
    int lane = t & 63, wv = t >> 6;
    int wr = wv >> 1, wc = wv & 1;
    f32x4 acc[4][4];
    #pragma unroll
    for (int m = 0; m < 4; ++m)
        #pragma unroll
        for (int n = 0; n < 4; ++n) acc[m][n] = f32x4{0.f, 0.f, 0.f, 0.f};

    for (int k0 = 0; k0 < K; k0 += 32) {
        if (A_F32) {
            const float* A = (const float*)A_;
            #pragma unroll
            for (int p = 0; p < 4; ++p) {
                int r = p * 32 + (t >> 3), c = (t & 7) * 4;
                int gr = brow + r;
                float4 v = make_float4(0.f, 0.f, 0.f, 0.f);
                if (gr < M) v = *(const float4*)(A + (size_t)gr * K + k0 + c);
                u16* dp = &As[r * 40 + c];
                dp[0] = f2bf_u16(v.x); dp[1] = f2bf_u16(v.y);
                dp[2] = f2bf_u16(v.z); dp[3] = f2bf_u16(v.w);
            }
        } else {
            const u16* A = (const u16*)A_;
            #pragma unroll
            for (int p = 0; p < 2; ++p) {
                int r = p * 64 + (t >> 2), c = (t & 3) * 8;
                int gr = brow + r;
                uint4 v = make_uint4(0u, 0u, 0u, 0u);
                if (gr < M) v = *(const uint4*)(A + (size_t)gr * K + k0 + c);
                *(uint4*)&As[r * 40 + c] = v;
            }
        }
        #pragma unroll
        for (int p = 0; p < 2; ++p) {
            int r = p * 64 + (t >> 2), c = (t & 3) * 8;
            int gn = bcol + r;
            uint4 v = make_uint4(0u, 0u, 0u, 0u);
            if (gn < N) v = *(const uint4*)(Bt + (size_t)gn * K + k0 + c);
            *(uint4*)&Bs[r * 40 + c] = v;
        }
        __syncthreads();
        int kg = (lane >> 4) * 8;
        short8 av[4], bv[4];
        #pragma unroll
        for (int m = 0; m < 4; ++m)
            av[m] = *(const short8*)&As[(wr * 64 + m * 16 + (lane & 15)) * 40 + kg];
        #pragma unroll
        for (int n = 0; n < 4; ++n)
            bv[n] = *(const short8*)&Bs[(wc * 64 + n * 16 + (lane & 15)) * 40 + kg];
        #pragma unroll
        for (int m = 0; m < 4; ++m)
            #pragma unroll
            for (int n = 0; n < 4; ++n)
                acc[m][n] = __builtin_amdgcn_mfma_f32_16x16x32_bf16(av[m], bv[n], acc[m][n], 0, 0, 0);
        __syncthreads();
    }
    #pragma unroll
    for (int m = 0; m < 4; ++m) {
        #pragma unroll
        for (int n = 0; n < 4; ++n) {
            #pragma unroll
            for (int r = 0; r < 4; ++r) {
                int row = brow + wr * 64 + m * 16 + (lane >> 4) * 4 + r;
                int col = bcol + wc * 64 + n * 16 + (lane & 15);
                if (row < M && col < N) {
                    float v = acc[m][n][r];
                    if (TRIANG && col < row) v = 0.f;
                    if (OUT_BF16) ((u16*)C_)[(size_t)row * N + col] = f2bf_u16(v);
                    else Cf[(size_t)row * N + col] = v;
                }
            }
        }
    }
}

// ---------------- aggregation: out[d] = nd[d] * sum_{e in in(d)} ns[s]*Y[s] + b ----------------

template<int F, bool RELU, bool OUT_BF16>
__global__ __launch_bounds__(256)
void agg_kernel(const u16* __restrict__ Y, const int* __restrict__ row_ptr,
                const int* __restrict__ csr_src, const float* __restrict__ ns,
                const float* __restrict__ nd, const float* __restrict__ bias,
                void* __restrict__ out, int n_nodes) {
    constexpr int VPL = F / 64;  // values per lane
    int lane = threadIdx.x & 63;
    int node = blockIdx.x * 4 + (threadIdx.x >> 6);
    if (node >= n_nodes) return;
    int e0 = row_ptr[node], e1 = row_ptr[node + 1];
    float acc[VPL];
    #pragma unroll
    for (int j = 0; j < VPL; ++j) acc[j] = 0.f;
    for (int e = e0; e < e1; ++e) {
        int s = csr_src[e];
        float w = ns[s];
        const u16* rp = Y + (size_t)s * F + lane * VPL;
        if (VPL == 4) {
            uint2 d = *(const uint2*)rp;
            acc[0] += w * bfu(d.x & 0xffffu);
            acc[1] += w * bfu(d.x >> 16);
            acc[2] += w * bfu(d.y & 0xffffu);
            acc[3] += w * bfu(d.y >> 16);
        } else {
            u32 d = *(const u32*)rp;
            acc[0] += w * bfu(d & 0xffffu);
            acc[1] += w * bfu(d >> 16);
        }
    }
    float ndv = nd[node];
    #pragma unroll
    for (int j = 0; j < VPL; ++j) {
        float o = acc[j] * ndv + bias[lane * VPL + j];
        if (RELU) o = fmaxf(o, 0.f);
        if (OUT_BF16) ((u16*)out)[(size_t)node * F + lane * VPL + j] = f2bf_u16(o);
        else ((float*)out)[(size_t)node * F + lane * VPL + j] = o;
    }
}

// ---------------- normalize + build R = [ (a+b)/2 , (a-b)/(2*sqrt(3)) ] ----------------

__global__ __launch_bounds__(256)
void build_r_kernel(const float* __restrict__ H2a, const float* __restrict__ H2b,
                    const int* __restrict__ index, u16* __restrict__ R) {
    int lane = threadIdx.x & 63;
    int row = blockIdx.x * 4 + (threadIdx.x >> 6);
    int g = index[row];
    float2 a = *(const float2*)(H2a + (size_t)g * 128 + lane * 2);
    float2 b = *(const float2*)(H2b + (size_t)g * 128 + lane * 2);
    float sa = a.x * a.x + a.y * a.y;
    float sb = b.x * b.x + b.y * b.y;
    #pragma unroll
    for (int d = 1; d < 64; d <<= 1) {
        sa += __shfl_xor(sa, d, 64);
        sb += __shfl_xor(sb, d, 64);
    }
    float inva = 1.f / fmaxf(sqrtf(sa), 1e-12f);
    float invb = 1.f / fmaxf(sqrtf(sb), 1e-12f);
    float ax = a.x * inva, ay = a.y * inva;
    float bx = b.x * invb, by = b.y * invb;
    const float c2 = 0.5f, c3 = 0.28867513459481287f;  // 1/(2*sqrt(3))
    u16* Rp = R + (size_t)row * 256;
    Rp[lane * 2]           = f2bf_u16((ax + bx) * c2);
    Rp[lane * 2 + 1]       = f2bf_u16((ay + by) * c2);
    Rp[128 + lane * 2]     = f2bf_u16((ax - bx) * c3);
    Rp[128 + lane * 2 + 1] = f2bf_u16((ay - by) * c3);
}

// ---------------- launch ----------------

extern "C" void kernel_launch(void* const* d_in, const int* in_sizes, int n_in,
                              void* d_out, int out_size, void* d_ws, size_t ws_size,
                              hipStream_t stream) {
    (void)in_sizes; (void)n_in; (void)out_size; (void)ws_size;
    const float* raw[2]  = {(const float*)d_in[0], (const float*)d_in[1]};
    const int*   srcs[2] = {(const int*)d_in[2], (const int*)d_in[4]};
    const int*   dsts[2] = {(const int*)d_in[3], (const int*)d_in[5]};
    const int*   index   = (const int*)d_in[6];
    const float* W1[2] = {(const float*)d_in[7],  (const float*)d_in[11]};
    const float* b1[2] = {(const float*)d_in[8],  (const float*)d_in[12]};
    const float* W2[2] = {(const float*)d_in[9],  (const float*)d_in[13]};
    const float* b2[2] = {(const float*)d_in[10], (const float*)d_in[14]};

    char* p = (char*)d_ws;
    auto alloc = [&](size_t bytes) -> char* {
        char* r = p;
        p += (bytes + 255) & ~(size_t)255;
        return r;
    };
    int* deg_out = (int*)alloc(NN * 4);
    int* deg_in  = (int*)alloc(NN * 4);
    float* ns    = (float*)alloc(NN * 4);
    float* nd    = (float*)alloc(NN * 4);
    int* row_ptr = (int*)alloc((NN + 1) * 4);
    int* cursor  = (int*)alloc((NN + 1) * 4);
    int* csr_src = (int*)alloc((size_t)NE * 4);
    u16* W1t     = (u16*)alloc((size_t)512 * 256 * 2);
    u16* W2t     = (u16*)alloc((size_t)256 * 128 * 2);
    u16* Y1      = (u16*)alloc((size_t)NN * 256 * 2);
    u16* H1      = (u16*)alloc((size_t)NN * 256 * 2);
    u16* Y2      = (u16*)alloc((size_t)NN * 128 * 2);
    float* H2a   = (float*)alloc((size_t)NN * 128 * 4);
    float* H2b   = (float*)alloc((size_t)NN * 128 * 4);
    u16* R       = (u16*)alloc((size_t)NIDX * 256 * 2);

    const int MT = (NN + 127) / 128;  // 391 row tiles

    for (int enc = 0; enc < 2; ++enc) {
        float* H2 = enc ? H2b : H2a;
        hipMemsetAsync(deg_out, 0, NN * 4, stream);
        hipMemsetAsync(deg_in, 0, NN * 4, stream);
        hist_kernel<<<(NE + 255) / 256, 256, 0, stream>>>(srcs[enc], dsts[enc], deg_out, deg_in, NE);
        norm_kernel<<<(NN + 255) / 256, 256, 0, stream>>>(deg_out, deg_in, ns, nd, NN);
        scan_kernel<<<1, 1024, 0, stream>>>(deg_in, row_ptr, cursor, NN);
        scatter_kernel<<<(NE + 255) / 256, 256, 0, stream>>>(srcs[enc], dsts[enc], cursor, csr_src, NE);
        convw_kernel<<<(512 * 256 + 255) / 256, 256, 0, stream>>>(W1[enc], W1t, 512, 256);
        convw_kernel<<<(256 * 128 + 255) / 256, 256, 0, stream>>>(W2[enc], W2t, 256, 128);
        // Y1 = raw @ W1   (f32 A converted on the fly)
        gemm_kernel<true, true, false><<<dim3(MT, 2), 256, 0, stream>>>(raw[enc], W1t, Y1, NN, 256, 512);
        // H1 = relu(nd * agg(ns * Y1) + b1), bf16
        agg_kernel<256, true, true><<<(NN + 3) / 4, 256, 0, stream>>>(Y1, row_ptr, csr_src, ns, nd, b1[enc], H1, NN);
        // Y2 = H1 @ W2
        gemm_kernel<false, true, false><<<dim3(MT, 1), 256, 0, stream>>>(H1, W2t, Y2, NN, 128, 256);
        // H2 = nd * agg(ns * Y2) + b2, f32
        agg_kernel<128, false, false><<<(NN + 3) / 4, 256, 0, stream>>>(Y2, row_ptr, csr_src, ns, nd, b2[enc], H2, NN);
    }
    // R = [ (c1n+c2n)/2 , (c1n-c2n)/(2*sqrt(3)) ]  (8192 x 256, bf16)
    build_r_kernel<<<NIDX / 4, 256, 0, stream>>>(H2a, H2b, index, R);
    // z = triu(R @ R^T)
    gemm_kernel<false, false, true><<<dim3(64, 64), 256, 0, stream>>>(R, R, (float*)d_out, NIDX, NIDX, 256);
}

// Round 2
// 1231.591 us; speedup vs baseline: 1.2538x; 1.2538x over previous
//
#include <hip/hip_runtime.h>
#include <hip/hip_bf16.h>

using u16 = unsigned short;
using u32 = unsigned int;

typedef __attribute__((ext_vector_type(8))) short short8;
typedef __attribute__((ext_vector_type(4))) float f32x4;

__device__ __forceinline__ u16 f2bf_u16(float f) {
    __hip_bfloat16 h = __float2bfloat16(f);
    return __builtin_bit_cast(u16, h);
}
__device__ __forceinline__ float bfu(u32 u) { return __uint_as_float(u << 16); }

static constexpr int NN = 50000;
static constexpr int NE = 1600000;
static constexpr int NIDX = 8192;

// ---------------- graph preprocessing ----------------

__global__ void hist_kernel(const int* __restrict__ src, const int* __restrict__ dst,
                            int* deg_out, int* deg_in, int E) {
    int e = blockIdx.x * blockDim.x + threadIdx.x;
    if (e < E) {
        atomicAdd(&deg_out[src[e]], 1);
        atomicAdd(&deg_in[dst[e]], 1);
    }
}

__global__ void norm_kernel(const int* __restrict__ deg_out, const int* __restrict__ deg_in,
                            float* ns, float* nd, int n) {
    int i = blockIdx.x * blockDim.x + threadIdx.x;
    if (i < n) {
        ns[i] = rsqrtf(fmaxf((float)deg_out[i], 1.f));
        nd[i] = rsqrtf(fmaxf((float)deg_in[i], 1.f));
    }
}

__global__ __launch_bounds__(1024)
void scan_kernel(const int* __restrict__ deg, int* row_ptr, int* cursor, int n) {
    __shared__ int wsum[16];
    __shared__ int carry;
    int t = threadIdx.x;
    int lane = t & 63, wid = t >> 6;
    if (t == 0) carry = 0;
    __syncthreads();
    for (int base = 0; base < n; base += 4096) {
        int i0 = base + t * 4;
        int4 v = make_int4(0, 0, 0, 0);
        if (i0 + 3 < n) v = *(const int4*)(deg + i0);
        else if (i0 < n) {
            v.x = deg[i0];
            if (i0 + 1 < n) v.y = deg[i0 + 1];
            if (i0 + 2 < n) v.z = deg[i0 + 2];
        }
        int s = v.x + v.y + v.z + v.w;
        int x = s;
        #pragma unroll
        for (int d = 1; d < 64; d <<= 1) {
            int y = __shfl_up(x, d, 64);
            if (lane >= d) x += y;
        }
        if (lane == 63) wsum[wid] = x;
        __syncthreads();
        if (t == 0) {
            int run = carry;
            #pragma unroll
            for (int w = 0; w < 16; ++w) { int q = wsum[w]; wsum[w] = run; run += q; }
            carry = run;
        }
        __syncthreads();
        if (i0 < n) {
            int excl = wsum[wid] + x - s;
            int p1 = excl + v.x, p2 = p1 + v.y, p3 = p2 + v.z;
            row_ptr[i0] = excl; cursor[i0] = excl;
            if (i0 + 1 < n) { row_ptr[i0 + 1] = p1; cursor[i0 + 1] = p1; }
            if (i0 + 2 < n) { row_ptr[i0 + 2] = p2; cursor[i0 + 2] = p2; }
            if (i0 + 3 < n) { row_ptr[i0 + 3] = p3; cursor[i0 + 3] = p3; }
        }
        __syncthreads();
    }
    if (t == 0) row_ptr[n] = carry;
}

__global__ void scatter_kernel(const int* __restrict__ src, const int* __restrict__ dst,
                               int* cursor, int* csr_src, int E) {
    int e = blockIdx.x * blockDim.x + threadIdx.x;
    if (e < E) {
        int pos = atomicAdd(&cursor[dst[e]], 1);
        csr_src[pos] = src[e];
    }
}

// W [K][N] f32  ->  Wt [N][K] bf16
__global__ void convw_kernel(const float* __restrict__ W, u16* Wt, int K, int N) {
    int idx = blockIdx.x * blockDim.x + threadIdx.x;
    if (idx < K * N) {
        int k = idx / N, n = idx - k * N;
        Wt[(size_t)n * K + k] = f2bf_u16(W[idx]);
    }
}

// ---------------- MFMA GEMM: C = A @ Bt^T (optionally row-scaled epilogue) ----------------
// A: [M][K] (f32 or bf16), Bt: [N][K] bf16, C: [M][N] (bf16 or f32)
// SCALE: C[row] *= rowscale[row] before store (used to fold ns into Y).
// TRIANG: A==Bt==R, write zeros for col<row, zero-fill blocks below diagonal.

template<bool A_F32, bool OUT_BF16, bool TRIANG, bool SCALE>
__global__ __launch_bounds__(256)
void gemm_kernel(const void* __restrict__ A_, const u16* __restrict__ Bt,
                 void* __restrict__ C_, const float* __restrict__ rowscale,
                 int M, int N, int K) {
    int it = blockIdx.x, jt = blockIdx.y;
    int t = threadIdx.x;
    int brow = it * 128, bcol = jt * 128;
    float* Cf = (float*)C_;
    if (TRIANG && jt < it) {
        #pragma unroll
        for (int p = 0; p < 16; ++p) {
            int idx = p * 256 + t;
            int r = idx >> 5, c4 = idx & 31;
            *(float4*)(Cf + (size_t)(brow + r) * N + bcol + c4 * 4) = make_float4(0.f, 0.f, 0.f, 0.f);
        }
        return;
    }
    __shared__ u16 As[128 * 40];
    __shared__ u16 Bs[128 * 40];
    int lane = t & 63, wv = t >> 6;
    int wr = wv >> 1, wc = wv & 1;
    f32x4 acc[4][4];
    #pragma unroll
    for (int m = 0; m < 4; ++m)
        #pragma unroll
        for (int n = 0; n < 4; ++n) acc[m][n] = f32x4{0.f, 0.f, 0.f, 0.f};

    for (int k0 = 0; k0 < K; k0 += 32) {
        if (A_F32) {
            const float* A = (const float*)A_;
            #pragma unroll
            for (int p = 0; p < 4; ++p) {
                int r = p * 32 + (t >> 3), c = (t & 7) * 4;
                int gr = brow + r;
                float4 v = make_float4(0.f, 0.f, 0.f, 0.f);
                if (gr < M) v = *(const float4*)(A + (size_t)gr * K + k0 + c);
                u16* dp = &As[r * 40 + c];
                dp[0] = f2bf_u16(v.x); dp[1] = f2bf_u16(v.y);
                dp[2] = f2bf_u16(v.z); dp[3] = f2bf_u16(v.w);
            }
        } else {
            const u16* A = (const u16*)A_;
            #pragma unroll
            for (int p = 0; p < 2; ++p) {
                int r = p * 64 + (t >> 2), c = (t & 3) * 8;
                int gr = brow + r;
                uint4 v = make_uint4(0u, 0u, 0u, 0u);
                if (gr < M) v = *(const uint4*)(A + (size_t)gr * K + k0 + c);
                *(uint4*)&As[r * 40 + c] = v;
            }
        }
        #pragma unroll
        for (int p = 0; p < 2; ++p) {
            int r = p * 64 + (t >> 2), c = (t & 3) * 8;
            int gn = bcol + r;
            uint4 v = make_uint4(0u, 0u, 0u, 0u);
            if (gn < N) v = *(const uint4*)(Bt + (size_t)gn * K + k0 + c);
            *(uint4*)&Bs[r * 40 + c] = v;
        }
        __syncthreads();
        int kg = (lane >> 4) * 8;
        short8 av[4], bv[4];
        #pragma unroll
        for (int m = 0; m < 4; ++m)
            av[m] = *(const short8*)&As[(wr * 64 + m * 16 + (lane & 15)) * 40 + kg];
        #pragma unroll
        for (int n = 0; n < 4; ++n)
            bv[n] = *(const short8*)&Bs[(wc * 64 + n * 16 + (lane & 15)) * 40 + kg];
        #pragma unroll
        for (int m = 0; m < 4; ++m)
            #pragma unroll
            for (int n = 0; n < 4; ++n)
                acc[m][n] = __builtin_amdgcn_mfma_f32_16x16x32_bf16(av[m], bv[n], acc[m][n], 0, 0, 0);
        __syncthreads();
    }
    #pragma unroll
    for (int m = 0; m < 4; ++m) {
        #pragma unroll
        for (int n = 0; n < 4; ++n) {
            #pragma unroll
            for (int r = 0; r < 4; ++r) {
                int row = brow + wr * 64 + m * 16 + (lane >> 4) * 4 + r;
                int col = bcol + wc * 64 + n * 16 + (lane & 15);
                if (row < M && col < N) {
                    float v = acc[m][n][r];
                    if (SCALE) v *= rowscale[row];
                    if (TRIANG && col < row) v = 0.f;
                    if (OUT_BF16) ((u16*)C_)[(size_t)row * N + col] = f2bf_u16(v);
                    else Cf[(size_t)row * N + col] = v;
                }
            }
        }
    }
}

// ---------------- aggregation: out[d] = nd[d] * sum_{e in in(d)} Y[s] + b ----------------
// (Y is pre-scaled by ns in the GEMM epilogue.)

template<int F, bool RELU, bool OUT_BF16>
__global__ __launch_bounds__(256)
void agg_kernel(const u16* __restrict__ Y, const int* __restrict__ row_ptr,
                const int* __restrict__ csr_src,
                const float* __restrict__ nd, const float* __restrict__ bias,
                void* __restrict__ out, int n_nodes) {
    constexpr int VPL = F / 64;  // values per lane
    int lane = threadIdx.x & 63;
    int node = blockIdx.x * 4 + (threadIdx.x >> 6);
    if (node >= n_nodes) return;
    int e0 = row_ptr[node], e1 = row_ptr[node + 1];
    float acc[VPL];
    #pragma unroll
    for (int j = 0; j < VPL; ++j) acc[j] = 0.f;
    const int off = lane * VPL;
    int e = e0;
    if (VPL == 4) {
        for (; e + 8 <= e1; e += 8) {
            uint2 d[8];
            #pragma unroll
            for (int u = 0; u < 8; ++u) {
                int s = csr_src[e + u];
                d[u] = *(const uint2*)(Y + (size_t)s * F + off);
            }
            #pragma unroll
            for (int u = 0; u < 8; ++u) {
                acc[0] += bfu(d[u].x & 0xffffu);
                acc[1] += bfu(d[u].x >> 16);
                acc[2] += bfu(d[u].y & 0xffffu);
                acc[3] += bfu(d[u].y >> 16);
            }
        }
        for (; e < e1; ++e) {
            int s = csr_src[e];
            uint2 d = *(const uint2*)(Y + (size_t)s * F + off);
            acc[0] += bfu(d.x & 0xffffu);
            acc[1] += bfu(d.x >> 16);
            acc[2] += bfu(d.y & 0xffffu);
            acc[3] += bfu(d.y >> 16);
        }
    } else {
        for (; e + 8 <= e1; e += 8) {
            u32 d[8];
            #pragma unroll
            for (int u = 0; u < 8; ++u) {
                int s = csr_src[e + u];
                d[u] = *(const u32*)(Y + (size_t)s * F + off);
            }
            #pragma unroll
            for (int u = 0; u < 8; ++u) {
                acc[0] += bfu(d[u] & 0xffffu);
                acc[1] += bfu(d[u] >> 16);
            }
        }
        for (; e < e1; ++e) {
            int s = csr_src[e];
            u32 d = *(const u32*)(Y + (size_t)s * F + off);
            acc[0] += bfu(d & 0xffffu);
            acc[1] += bfu(d >> 16);
        }
    }
    float ndv = nd[node];
    #pragma unroll
    for (int j = 0; j < VPL; ++j) {
        float o = acc[j] * ndv + bias[off + j];
        if (RELU) o = fmaxf(o, 0.f);
        if (OUT_BF16) ((u16*)out)[(size_t)node * F + off + j] = f2bf_u16(o);
        else ((float*)out)[(size_t)node * F + off + j] = o;
    }
}

// ---------------- normalize + build R = [ (a+b)/2 , (a-b)/(2*sqrt(3)) ] ----------------

__global__ __launch_bounds__(256)
void build_r_kernel(const float* __restrict__ H2a, const float* __restrict__ H2b,
                    const int* __restrict__ index, u16* __restrict__ R) {
    int lane = threadIdx.x & 63;
    int row = blockIdx.x * 4 + (threadIdx.x >> 6);
    int g = index[row];
    float2 a = *(const float2*)(H2a + (size_t)g * 128 + lane * 2);
    float2 b = *(const float2*)(H2b + (size_t)g * 128 + lane * 2);
    float sa = a.x * a.x + a.y * a.y;
    float sb = b.x * b.x + b.y * b.y;
    #pragma unroll
    for (int d = 1; d < 64; d <<= 1) {
        sa += __shfl_xor(sa, d, 64);
        sb += __shfl_xor(sb, d, 64);
    }
    float inva = 1.f / fmaxf(sqrtf(sa), 1e-12f);
    float invb = 1.f / fmaxf(sqrtf(sb), 1e-12f);
    float ax = a.x * inva, ay = a.y * inva;
    float bx = b.x * invb, by = b.y * invb;
    const float c2 = 0.5f, c3 = 0.28867513459481287f;  // 1/(2*sqrt(3))
    u16* Rp = R + (size_t)row * 256;
    Rp[lane * 2]           = f2bf_u16((ax + bx) * c2);
    Rp[lane * 2 + 1]       = f2bf_u16((ay + by) * c2);
    Rp[128 + lane * 2]     = f2bf_u16((ax - bx) * c3);
    Rp[128 + lane * 2 + 1] = f2bf_u16((ay - by) * c3);
}

// ---------------- launch ----------------

extern "C" void kernel_launch(void* const* d_in, const int* in_sizes, int n_in,
                              void* d_out, int out_size, void* d_ws, size_t ws_size,
                              hipStream_t stream) {
    (void)in_sizes; (void)n_in; (void)out_size; (void)ws_size;
    const float* raw[2]  = {(const float*)d_in[0], (const float*)d_in[1]};
    const int*   srcs[2] = {(const int*)d_in[2], (const int*)d_in[4]};
    const int*   dsts[2] = {(const int*)d_in[3], (const int*)d_in[5]};
    const int*   index   = (const int*)d_in[6];
    const float* W1[2] = {(const float*)d_in[7],  (const float*)d_in[11]};
    const float* b1[2] = {(const float*)d_in[8],  (const float*)d_in[12]};
    const float* W2[2] = {(const float*)d_in[9],  (const float*)d_in[13]};
    const float* b2[2] = {(const float*)d_in[10], (const float*)d_in[14]};

    char* p = (char*)d_ws;
    auto alloc = [&](size_t bytes) -> char* {
        char* r = p;
        p += (bytes + 255) & ~(size_t)255;
        return r;
    };
    int* deg_out = (int*)alloc(NN * 4);
    int* deg_in  = (int*)alloc(NN * 4);
    float* ns    = (float*)alloc(NN * 4);
    float* nd    = (float*)alloc(NN * 4);
    int* row_ptr = (int*)alloc((NN + 1) * 4);
    int* cursor  = (int*)alloc((NN + 1) * 4);
    int* csr_src = (int*)alloc((size_t)NE * 4);
    u16* W1t     = (u16*)alloc((size_t)512 * 256 * 2);
    u16* W2t     = (u16*)alloc((size_t)256 * 128 * 2);
    u16* Y1      = (u16*)alloc((size_t)NN * 256 * 2);
    u16* H1      = (u16*)alloc((size_t)NN * 256 * 2);
    u16* Y2      = (u16*)alloc((size_t)NN * 128 * 2);
    float* H2a   = (float*)alloc((size_t)NN * 128 * 4);
    float* H2b   = (float*)alloc((size_t)NN * 128 * 4);
    u16* R       = (u16*)alloc((size_t)NIDX * 256 * 2);

    const int MT = (NN + 127) / 128;  // 391 row tiles

    for (int enc = 0; enc < 2; ++enc) {
        float* H2 = enc ? H2b : H2a;
        hipMemsetAsync(deg_out, 0, NN * 4, stream);
        hipMemsetAsync(deg_in, 0, NN * 4, stream);
        hist_kernel<<<(NE + 255) / 256, 256, 0, stream>>>(srcs[enc], dsts[enc], deg_out, deg_in, NE);
        norm_kernel<<<(NN + 255) / 256, 256, 0, stream>>>(deg_out, deg_in, ns, nd, NN);
        scan_kernel<<<1, 1024, 0, stream>>>(deg_in, row_ptr, cursor, NN);
        scatter_kernel<<<(NE + 255) / 256, 256, 0, stream>>>(srcs[enc], dsts[enc], cursor, csr_src, NE);
        convw_kernel<<<(512 * 256 + 255) / 256, 256, 0, stream>>>(W1[enc], W1t, 512, 256);
        convw_kernel<<<(256 * 128 + 255) / 256, 256, 0, stream>>>(W2[enc], W2t, 256, 128);
        // Y1 = (raw @ W1) * ns[row]   (f32 A converted on the fly; ns folded in epilogue)
        gemm_kernel<true, true, false, true><<<dim3(MT, 2), 256, 0, stream>>>(raw[enc], W1t, Y1, ns, NN, 256, 512);
        // H1 = relu(nd * agg(Y1) + b1), bf16
        agg_kernel<256, true, true><<<(NN + 3) / 4, 256, 0, stream>>>(Y1, row_ptr, csr_src, nd, b1[enc], H1, NN);
        // Y2 = (H1 @ W2) * ns[row]
        gemm_kernel<false, true, false, true><<<dim3(MT, 1), 256, 0, stream>>>(H1, W2t, Y2, ns, NN, 128, 256);
        // H2 = nd * agg(Y2) + b2, f32
        agg_kernel<128, false, false><<<(NN + 3) / 4, 256, 0, stream>>>(Y2, row_ptr, csr_src, nd, b2[enc], H2, NN);
    }
    // R = [ (c1n+c2n)/2 , (c1n-c2n)/(2*sqrt(3)) ]  (8192 x 256, bf16)
    build_r_kernel<<<NIDX / 4, 256, 0, stream>>>(H2a, H2b, index, R);
    // z = triu(R @ R^T)
    gemm_kernel<false, false, true, false><<<dim3(64, 64), 256, 0, stream>>>(R, R, (float*)d_out, nullptr, NIDX, NIDX, 256);
}

// Round 3
// 1159.379 us; speedup vs baseline: 1.3319x; 1.0623x over previous
//
#include <hip/hip_runtime.h>
#include <hip/hip_bf16.h>

using u16 = unsigned short;
using u32 = unsigned int;

typedef __attribute__((ext_vector_type(8))) short short8;
typedef __attribute__((ext_vector_type(4))) float f32x4;

__device__ __forceinline__ u16 f2bf_u16(float f) {
    __hip_bfloat16 h = __float2bfloat16(f);
    return __builtin_bit_cast(u16, h);
}
__device__ __forceinline__ float bfu(u32 u) { return __uint_as_float(u << 16); }

static constexpr int NN = 50000;
static constexpr int NE = 1600000;
static constexpr int NIDX = 8192;

// deg_all / norms layout: [enc*2+0] = out(src) arrays, [enc*2+1] = in(dst) arrays, each NN.

// ---------------- graph preprocessing (both encoders in one launch) ----------------

__global__ void hist_kernel(const int* __restrict__ s1, const int* __restrict__ d1,
                            const int* __restrict__ s2, const int* __restrict__ d2,
                            int* __restrict__ deg_all, int E) {
    int e = blockIdx.x * blockDim.x + threadIdx.x;
    const int* s = s1; const int* d = d1; int base = 0;
    if (e >= E) { e -= E; s = s2; d = d2; base = 2 * NN; }
    if (e < E) {
        atomicAdd(&deg_all[base + s[e]], 1);
        atomicAdd(&deg_all[base + NN + d[e]], 1);
    }
}

__global__ void norm_kernel(const int* __restrict__ deg_all, float* __restrict__ norms, int n4) {
    int i = blockIdx.x * blockDim.x + threadIdx.x;
    if (i < n4) norms[i] = rsqrtf(fmaxf((float)deg_all[i], 1.f));
}

// one block per encoder (blockIdx.x = enc); exclusive scan of deg_in -> row_ptr, cursor
__global__ __launch_bounds__(1024)
void scan_kernel(const int* __restrict__ deg_all, int* __restrict__ rp_all,
                 int* __restrict__ cur_all, int n) {
    int enc = blockIdx.x;
    const int* deg = deg_all + (size_t)(2 * enc + 1) * NN;
    int* row_ptr = rp_all + (size_t)enc * (NN + 1);
    int* cursor = cur_all + (size_t)enc * (NN + 1);
    __shared__ int wsum[16];
    __shared__ int carry;
    int t = threadIdx.x;
    int lane = t & 63, wid = t >> 6;
    if (t == 0) carry = 0;
    __syncthreads();
    for (int base = 0; base < n; base += 4096) {
        int i0 = base + t * 4;
        int4 v = make_int4(0, 0, 0, 0);
        if (i0 + 3 < n) v = *(const int4*)(deg + i0);
        else if (i0 < n) {
            v.x = deg[i0];
            if (i0 + 1 < n) v.y = deg[i0 + 1];
            if (i0 + 2 < n) v.z = deg[i0 + 2];
        }
        int s = v.x + v.y + v.z + v.w;
        int x = s;
        #pragma unroll
        for (int d = 1; d < 64; d <<= 1) {
            int y = __shfl_up(x, d, 64);
            if (lane >= d) x += y;
        }
        if (lane == 63) wsum[wid] = x;
        __syncthreads();
        if (t == 0) {
            int run = carry;
            #pragma unroll
            for (int w = 0; w < 16; ++w) { int q = wsum[w]; wsum[w] = run; run += q; }
            carry = run;
        }
        __syncthreads();
        if (i0 < n) {
            int excl = wsum[wid] + x - s;
            int p1 = excl + v.x, p2 = p1 + v.y, p3 = p2 + v.z;
            row_ptr[i0] = excl; cursor[i0] = excl;
            if (i0 + 1 < n) { row_ptr[i0 + 1] = p1; cursor[i0 + 1] = p1; }
            if (i0 + 2 < n) { row_ptr[i0 + 2] = p2; cursor[i0 + 2] = p2; }
            if (i0 + 3 < n) { row_ptr[i0 + 3] = p3; cursor[i0 + 3] = p3; }
        }
        __syncthreads();
    }
    if (t == 0) row_ptr[n] = carry;
}

__global__ void scatter_kernel(const int* __restrict__ s1, const int* __restrict__ d1,
                               const int* __restrict__ s2, const int* __restrict__ d2,
                               int* __restrict__ cur_all, int* __restrict__ csr_all, int E) {
    int e = blockIdx.x * blockDim.x + threadIdx.x;
    const int* s = s1; const int* d = d1; int enc = 0;
    if (e >= E) { e -= E; s = s2; d = d2; enc = 1; }
    if (e < E) {
        int pos = atomicAdd(&cur_all[(size_t)enc * (NN + 1) + d[e]], 1);
        csr_all[(size_t)enc * NE + pos] = s[e];
    }
}

// all four weight matrices: blockIdx.y = {W1a, W1b, W2a, W2b};  W [K][N] f32 -> Wt [N][K] bf16
__global__ void convw_kernel(const float* __restrict__ W1a, const float* __restrict__ W1b,
                             const float* __restrict__ W2a, const float* __restrict__ W2b,
                             u16* __restrict__ W1t_all, u16* __restrict__ W2t_all) {
    int mat = blockIdx.y;
    int idx = blockIdx.x * blockDim.x + threadIdx.x;
    const float* W; u16* Wt; int K, N;
    if (mat < 2) { W = mat ? W1b : W1a; Wt = W1t_all + (size_t)mat * 512 * 256; K = 512; N = 256; }
    else         { W = (mat == 3) ? W2b : W2a; Wt = W2t_all + (size_t)(mat - 2) * 256 * 128; K = 256; N = 128; }
    if (idx < K * N) {
        int k = idx / N, n = idx - k * N;
        Wt[(size_t)n * K + k] = f2bf_u16(W[idx]);
    }
}

// ---------------- MFMA GEMM: C = A @ Bt^T (dual-encoder via blockIdx.z) ----------------
// A: [M][K] (f32 or bf16), Bt: [N][K] bf16, C: [M][N] (bf16 or f32)
// SCALE: C[row] *= rowscale[row] (folds ns into Y).  TRIANG: z = triu(R R^T), nontemporal.

template<bool A_F32, bool OUT_BF16, bool TRIANG, bool SCALE>
__global__ __launch_bounds__(256)
void gemm_kernel(const void* __restrict__ A0_, const void* __restrict__ A1_,
                 const u16* __restrict__ Bt0, const u16* __restrict__ Bt1,
                 void* __restrict__ C0_, void* __restrict__ C1_,
                 const float* __restrict__ rs0, const float* __restrict__ rs1,
                 int M, int N, int K) {
    int enc = blockIdx.z;
    const void* A_ = enc ? A1_ : A0_;
    const u16* Bt = enc ? Bt1 : Bt0;
    void* C_ = enc ? C1_ : C0_;
    const float* rowscale = enc ? rs1 : rs0;

    int it = blockIdx.x, jt = blockIdx.y;
    int t = threadIdx.x;
    int brow = it * 128, bcol = jt * 128;
    float* Cf = (float*)C_;
    if (TRIANG && jt < it) {
        f32x4 z = {0.f, 0.f, 0.f, 0.f};
        #pragma unroll
        for (int p = 0; p < 16; ++p) {
            int idx = p * 256 + t;
            int r = idx >> 5, c4 = idx & 31;
            __builtin_nontemporal_store(z, (f32x4*)(Cf + (size_t)(brow + r) * N + bcol + c4 * 4));
        }
        return;
    }
    __shared__ u16 As[128 * 40];
    __shared__ u16 Bs[128 * 40];
    int lane = t & 63, wv = t >> 6;
    int wr = wv >> 1, wc = wv & 1;
    f32x4 acc[4][4];
    #pragma unroll
    for (int m = 0; m < 4; ++m)
        #pragma unroll
        for (int n = 0; n < 4; ++n) acc[m][n] = f32x4{0.f, 0.f, 0.f, 0.f};

    for (int k0 = 0; k0 < K; k0 += 32) {
        if (A_F32) {
            const float* A = (const float*)A_;
            #pragma unroll
            for (int p = 0; p < 4; ++p) {
                int r = p * 32 + (t >> 3), c = (t & 7) * 4;
                int gr = brow + r;
                float4 v = make_float4(0.f, 0.f, 0.f, 0.f);
                if (gr < M) v = *(const float4*)(A + (size_t)gr * K + k0 + c);
                u32 lo = (u32)f2bf_u16(v.x) | ((u32)f2bf_u16(v.y) << 16);
                u32 hi = (u32)f2bf_u16(v.z) | ((u32)f2bf_u16(v.w) << 16);
                *(uint2*)&As[r * 40 + c] = make_uint2(lo, hi);
            }
        } else {
            const u16* A = (const u16*)A_;
            #pragma unroll
            for (int p = 0; p < 2; ++p) {
                int r = p * 64 + (t >> 2), c = (t & 3) * 8;
                int gr = brow + r;
                uint4 v = make_uint4(0u, 0u, 0u, 0u);
                if (gr < M) v = *(const uint4*)(A + (size_t)gr * K + k0 + c);
                *(uint4*)&As[r * 40 + c] = v;
            }
        }
        #pragma unroll
        for (int p = 0; p < 2; ++p) {
            int r = p * 64 + (t >> 2), c = (t & 3) * 8;
            int gn = bcol + r;
            uint4 v = make_uint4(0u, 0u, 0u, 0u);
            if (gn < N) v = *(const uint4*)(Bt + (size_t)gn * K + k0 + c);
            *(uint4*)&Bs[r * 40 + c] = v;
        }
        __syncthreads();
        int kg = (lane >> 4) * 8;
        short8 av[4], bv[4];
        #pragma unroll
        for (int m = 0; m < 4; ++m)
            av[m] = *(const short8*)&As[(wr * 64 + m * 16 + (lane & 15)) * 40 + kg];
        #pragma unroll
        for (int n = 0; n < 4; ++n)
            bv[n] = *(const short8*)&Bs[(wc * 64 + n * 16 + (lane & 15)) * 40 + kg];
        #pragma unroll
        for (int m = 0; m < 4; ++m)
            #pragma unroll
            for (int n = 0; n < 4; ++n)
                acc[m][n] = __builtin_amdgcn_mfma_f32_16x16x32_bf16(av[m], bv[n], acc[m][n], 0, 0, 0);
        __syncthreads();
    }
    #pragma unroll
    for (int m = 0; m < 4; ++m) {
        #pragma unroll
        for (int n = 0; n < 4; ++n) {
            #pragma unroll
            for (int r = 0; r < 4; ++r) {
                int row = brow + wr * 64 + m * 16 + (lane >> 4) * 4 + r;
                int col = bcol + wc * 64 + n * 16 + (lane & 15);
                if (row < M && col < N) {
                    float v = acc[m][n][r];
                    if (SCALE) v *= rowscale[row];
                    if (TRIANG) {
                        if (col < row) v = 0.f;
                        __builtin_nontemporal_store(v, Cf + (size_t)row * N + col);
                    } else if (OUT_BF16) {
                        ((u16*)C_)[(size_t)row * N + col] = f2bf_u16(v);
                    } else {
                        Cf[(size_t)row * N + col] = v;
                    }
                }
            }
        }
    }
}

// ---------------- aggregation: out[d] = nd[d] * sum_{e in in(d)} Y[s] + b ----------------
// (Y pre-scaled by ns in GEMM epilogue.)  blockIdx.y = enc.

template<int F, bool RELU, bool OUT_BF16>
__global__ __launch_bounds__(256)
void agg_kernel(const u16* __restrict__ Yall, const int* __restrict__ rp_all,
                const int* __restrict__ csr_all, const float* __restrict__ norms,
                const float* __restrict__ bias0, const float* __restrict__ bias1,
                void* __restrict__ out_all, int n_nodes) {
    constexpr int VPL = F / 64;  // values per lane
    int enc = blockIdx.y;
    const u16* Y = Yall + (size_t)enc * n_nodes * F;
    const int* row_ptr = rp_all + (size_t)enc * (n_nodes + 1);
    const int* csr = csr_all + (size_t)enc * NE;
    const float* nd = norms + (size_t)(2 * enc + 1) * NN;
    const float* bias = enc ? bias1 : bias0;

    int lane = threadIdx.x & 63;
    int node = blockIdx.x * 4 + (threadIdx.x >> 6);
    if (node >= n_nodes) return;
    int e0 = row_ptr[node], e1 = row_ptr[node + 1];
    float acc[VPL];
    #pragma unroll
    for (int j = 0; j < VPL; ++j) acc[j] = 0.f;
    const int off = lane * VPL;

    int e = e0;
    // peel to 16B alignment of csr+e
    for (; e < e1 && (e & 3) != 0; ++e) {
        int s = csr[e];
        if (VPL == 4) {
            uint2 d = *(const uint2*)(Y + (size_t)s * F + off);
            acc[0] += bfu(d.x & 0xffffu); acc[1] += bfu(d.x >> 16);
            acc[2] += bfu(d.y & 0xffffu); acc[3] += bfu(d.y >> 16);
        } else {
            u32 d = *(const u32*)(Y + (size_t)s * F + off);
            acc[0] += bfu(d & 0xffffu); acc[1] += bfu(d >> 16);
        }
    }
    for (; e + 8 <= e1; e += 8) {
        int4 ia = *(const int4*)(csr + e);
        int4 ib = *(const int4*)(csr + e + 4);
        if (VPL == 4) {
            uint2 d0 = *(const uint2*)(Y + (size_t)ia.x * F + off);
            uint2 d1 = *(const uint2*)(Y + (size_t)ia.y * F + off);
            uint2 d2 = *(const uint2*)(Y + (size_t)ia.z * F + off);
            uint2 d3 = *(const uint2*)(Y + (size_t)ia.w * F + off);
            uint2 d4 = *(const uint2*)(Y + (size_t)ib.x * F + off);
            uint2 d5 = *(const uint2*)(Y + (size_t)ib.y * F + off);
            uint2 d6 = *(const uint2*)(Y + (size_t)ib.z * F + off);
            uint2 d7 = *(const uint2*)(Y + (size_t)ib.w * F + off);
            acc[0] += bfu(d0.x & 0xffffu); acc[1] += bfu(d0.x >> 16); acc[2] += bfu(d0.y & 0xffffu); acc[3] += bfu(d0.y >> 16);
            acc[0] += bfu(d1.x & 0xffffu); acc[1] += bfu(d1.x >> 16); acc[2] += bfu(d1.y & 0xffffu); acc[3] += bfu(d1.y >> 16);
            acc[0] += bfu(d2.x & 0xffffu); acc[1] += bfu(d2.x >> 16); acc[2] += bfu(d2.y & 0xffffu); acc[3] += bfu(d2.y >> 16);
            acc[0] += bfu(d3.x & 0xffffu); acc[1] += bfu(d3.x >> 16); acc[2] += bfu(d3.y & 0xffffu); acc[3] += bfu(d3.y >> 16);
            acc[0] += bfu(d4.x & 0xffffu); acc[1] += bfu(d4.x >> 16); acc[2] += bfu(d4.y & 0xffffu); acc[3] += bfu(d4.y >> 16);
            acc[0] += bfu(d5.x & 0xffffu); acc[1] += bfu(d5.x >> 16); acc[2] += bfu(d5.y & 0xffffu); acc[3] += bfu(d5.y >> 16);
            acc[0] += bfu(d6.x & 0xffffu); acc[1] += bfu(d6.x >> 16); acc[2] += bfu(d6.y & 0xffffu); acc[3] += bfu(d6.y >> 16);
            acc[0] += bfu(d7.x & 0xffffu); acc[1] += bfu(d7.x >> 16); acc[2] += bfu(d7.y & 0xffffu); acc[3] += bfu(d7.y >> 16);
        } else {
            u32 d0 = *(const u32*)(Y + (size_t)ia.x * F + off);
            u32 d1 = *(const u32*)(Y + (size_t)ia.y * F + off);
            u32 d2 = *(const u32*)(Y + (size_t)ia.z * F + off);
            u32 d3 = *(const u32*)(Y + (size_t)ia.w * F + off);
            u32 d4 = *(const u32*)(Y + (size_t)ib.x * F + off);
            u32 d5 = *(const u32*)(Y + (size_t)ib.y * F + off);
            u32 d6 = *(const u32*)(Y + (size_t)ib.z * F + off);
            u32 d7 = *(const u32*)(Y + (size_t)ib.w * F + off);
            acc[0] += bfu(d0 & 0xffffu); acc[1] += bfu(d0 >> 16);
            acc[0] += bfu(d1 & 0xffffu); acc[1] += bfu(d1 >> 16);
            acc[0] += bfu(d2 & 0xffffu); acc[1] += bfu(d2 >> 16);
            acc[0] += bfu(d3 & 0xffffu); acc[1] += bfu(d3 >> 16);
            acc[0] += bfu(d4 & 0xffffu); acc[1] += bfu(d4 >> 16);
            acc[0] += bfu(d5 & 0xffffu); acc[1] += bfu(d5 >> 16);
            acc[0] += bfu(d6 & 0xffffu); acc[1] += bfu(d6 >> 16);
            acc[0] += bfu(d7 & 0xffffu); acc[1] += bfu(d7 >> 16);
        }
    }
    for (; e < e1; ++e) {
        int s = csr[e];
        if (VPL == 4) {
            uint2 d = *(const uint2*)(Y + (size_t)s * F + off);
            acc[0] += bfu(d.x & 0xffffu); acc[1] += bfu(d.x >> 16);
            acc[2] += bfu(d.y & 0xffffu); acc[3] += bfu(d.y >> 16);
        } else {
            u32 d = *(const u32*)(Y + (size_t)s * F + off);
            acc[0] += bfu(d & 0xffffu); acc[1] += bfu(d >> 16);
        }
    }

    float ndv = nd[node];
    #pragma unroll
    for (int j = 0; j < VPL; ++j) {
        float o = acc[j] * ndv + bias[off + j];
        if (RELU) o = fmaxf(o, 0.f);
        if (OUT_BF16) ((u16*)out_all)[(size_t)enc * n_nodes * F + (size_t)node * F + off + j] = f2bf_u16(o);
        else ((float*)out_all)[(size_t)enc * n_nodes * F + (size_t)node * F + off + j] = o;
    }
}

// ---------------- normalize + build R = [ (a+b)/2 , (a-b)/(2*sqrt(3)) ] ----------------

__global__ __launch_bounds__(256)
void build_r_kernel(const float* __restrict__ H2a, const float* __restrict__ H2b,
                    const int* __restrict__ index, u16* __restrict__ R) {
    int lane = threadIdx.x & 63;
    int row = blockIdx.x * 4 + (threadIdx.x >> 6);
    int g = index[row];
    float2 a = *(const float2*)(H2a + (size_t)g * 128 + lane * 2);
    float2 b = *(const float2*)(H2b + (size_t)g * 128 + lane * 2);
    float sa = a.x * a.x + a.y * a.y;
    float sb = b.x * b.x + b.y * b.y;
    #pragma unroll
    for (int d = 1; d < 64; d <<= 1) {
        sa += __shfl_xor(sa, d, 64);
        sb += __shfl_xor(sb, d, 64);
    }
    float inva = 1.f / fmaxf(sqrtf(sa), 1e-12f);
    float invb = 1.f / fmaxf(sqrtf(sb), 1e-12f);
    float ax = a.x * inva, ay = a.y * inva;
    float bx = b.x * invb, by = b.y * invb;
    const float c2 = 0.5f, c3 = 0.28867513459481287f;  // 1/(2*sqrt(3))
    u16* Rp = R + (size_t)row * 256;
    Rp[lane * 2]           = f2bf_u16((ax + bx) * c2);
    Rp[lane * 2 + 1]       = f2bf_u16((ay + by) * c2);
    Rp[128 + lane * 2]     = f2bf_u16((ax - bx) * c3);
    Rp[128 + lane * 2 + 1] = f2bf_u16((ay - by) * c3);
}

// ---------------- launch ----------------

extern "C" void kernel_launch(void* const* d_in, const int* in_sizes, int n_in,
                              void* d_out, int out_size, void* d_ws, size_t ws_size,
                              hipStream_t stream) {
    (void)in_sizes; (void)n_in; (void)out_size; (void)ws_size;
    const float* raw[2]  = {(const float*)d_in[0], (const float*)d_in[1]};
    const int* src1 = (const int*)d_in[2], *dst1 = (const int*)d_in[3];
    const int* src2 = (const int*)d_in[4], *dst2 = (const int*)d_in[5];
    const int* index = (const int*)d_in[6];
    const float* W1[2] = {(const float*)d_in[7],  (const float*)d_in[11]};
    const float* b1[2] = {(const float*)d_in[8],  (const float*)d_in[12]};
    const float* W2[2] = {(const float*)d_in[9],  (const float*)d_in[13]};
    const float* b2[2] = {(const float*)d_in[10], (const float*)d_in[14]};

    char* p = (char*)d_ws;
    auto alloc = [&](size_t bytes) -> char* {
        char* r = p;
        p += (bytes + 255) & ~(size_t)255;
        return r;
    };
    int*   deg_all = (int*)alloc((size_t)4 * NN * 4);
    float* norms   = (float*)alloc((size_t)4 * NN * 4);
    int*   rp_all  = (int*)alloc((size_t)2 * (NN + 1) * 4);
    int*   cur_all = (int*)alloc((size_t)2 * (NN + 1) * 4);
    int*   csr_all = (int*)alloc((size_t)2 * NE * 4);
    u16*   W1t     = (u16*)alloc((size_t)2 * 512 * 256 * 2);
    u16*   W2t     = (u16*)alloc((size_t)2 * 256 * 128 * 2);
    u16*   Y1      = (u16*)alloc((size_t)2 * NN * 256 * 2);
    u16*   H1      = (u16*)alloc((size_t)2 * NN * 256 * 2);
    u16*   Y2      = (u16*)alloc((size_t)2 * NN * 128 * 2);
    float* H2      = (float*)alloc((size_t)2 * NN * 128 * 4);
    u16*   R       = (u16*)alloc((size_t)NIDX * 256 * 2);

    const int MT = (NN + 127) / 128;  // 391 row tiles

    hipMemsetAsync(deg_all, 0, (size_t)4 * NN * 4, stream);
    hist_kernel<<<(2 * NE + 255) / 256, 256, 0, stream>>>(src1, dst1, src2, dst2, deg_all, NE);
    norm_kernel<<<(4 * NN + 255) / 256, 256, 0, stream>>>(deg_all, norms, 4 * NN);
    scan_kernel<<<2, 1024, 0, stream>>>(deg_all, rp_all, cur_all, NN);
    scatter_kernel<<<(2 * NE + 255) / 256, 256, 0, stream>>>(src1, dst1, src2, dst2, cur_all, csr_all, NE);
    convw_kernel<<<dim3((512 * 256 + 255) / 256, 4), 256, 0, stream>>>(W1[0], W1[1], W2[0], W2[1], W1t, W2t);

    // Y1 = (raw @ W1) * ns[row]   (both encoders; f32 A converted on the fly)
    gemm_kernel<true, true, false, true><<<dim3(MT, 2, 2), 256, 0, stream>>>(
        raw[0], raw[1], W1t, W1t + (size_t)512 * 256, Y1, Y1 + (size_t)NN * 256,
        norms, norms + (size_t)2 * NN, NN, 256, 512);
    // H1 = relu(nd * agg(Y1) + b1), bf16
    agg_kernel<256, true, true><<<dim3((NN + 3) / 4, 2), 256, 0, stream>>>(
        Y1, rp_all, csr_all, norms, b1[0], b1[1], H1, NN);
    // Y2 = (H1 @ W2) * ns[row]
    gemm_kernel<false, true, false, true><<<dim3(MT, 1, 2), 256, 0, stream>>>(
        H1, H1 + (size_t)NN * 256, W2t, W2t + (size_t)256 * 128, Y2, Y2 + (size_t)NN * 128,
        norms, norms + (size_t)2 * NN, NN, 128, 256);
    // H2 = nd * agg(Y2) + b2, f32
    agg_kernel<128, false, false><<<dim3((NN + 3) / 4, 2), 256, 0, stream>>>(
        Y2, rp_all, csr_all, norms, b2[0], b2[1], H2, NN);

    // R = [ (c1n+c2n)/2 , (c1n-c2n)/(2*sqrt(3)) ]  (8192 x 256, bf16)
    build_r_kernel<<<NIDX / 4, 256, 0, stream>>>(H2, H2 + (size_t)NN * 128, index, R);
    // z = triu(R @ R^T), nontemporal f32 output
    gemm_kernel<false, false, true, false><<<dim3(64, 64, 1), 256, 0, stream>>>(
        R, R, R, R, (float*)d_out, (float*)d_out, nullptr, nullptr, NIDX, NIDX, 256);
}

// Round 4
// 1039.005 us; speedup vs baseline: 1.4862x; 1.1159x over previous
//
#include <hip/hip_runtime.h>
#include <hip/hip_bf16.h>

using u16 = unsigned short;
using u32 = unsigned int;

typedef __attribute__((ext_vector_type(8))) short short8;
typedef __attribute__((ext_vector_type(4))) float f32x4;

__device__ __forceinline__ u16 f2bf_u16(float f) {
    __hip_bfloat16 h = __float2bfloat16(f);
    return __builtin_bit_cast(u16, h);
}
__device__ __forceinline__ float bfu(u32 u) { return __uint_as_float(u << 16); }

static constexpr int NN = 50000;
static constexpr int NE = 1600000;
static constexpr int NIDX = 8192;
static constexpr int NRANGE = 8;              // = #XCDs; range r -> blockIdx%8 -> XCD r
static constexpr int RN = NN / NRANGE;        // 6250 nodes per range

// deg_all / norms layout: [enc*2+0] = out(src) arrays, [enc*2+1] = in(dst) arrays, each NN.

// ---------------- graph preprocessing (both encoders in one launch) ----------------

__global__ void hist_kernel(const int* __restrict__ s1, const int* __restrict__ d1,
                            const int* __restrict__ s2, const int* __restrict__ d2,
                            int* __restrict__ deg_all, int E) {
    int e = blockIdx.x * blockDim.x + threadIdx.x;
    const int* s = s1; const int* d = d1; int base = 0;
    if (e >= E) { e -= E; s = s2; d = d2; base = 2 * NN; }
    if (e < E) {
        atomicAdd(&deg_all[base + s[e]], 1);
        atomicAdd(&deg_all[base + NN + d[e]], 1);
    }
}

__global__ void norm_kernel(const int* __restrict__ deg_all, float* __restrict__ norms, int n4) {
    int i = blockIdx.x * blockDim.x + threadIdx.x;
    if (i < n4) norms[i] = rsqrtf(fmaxf((float)deg_all[i], 1.f));
}

// one block per encoder (blockIdx.x = enc); exclusive scan of deg_in -> row_ptr, cursor
__global__ __launch_bounds__(1024)
void scan_kernel(const int* __restrict__ deg_all, int* __restrict__ rp_all,
                 int* __restrict__ cur_all, int n) {
    int enc = blockIdx.x;
    const int* deg = deg_all + (size_t)(2 * enc + 1) * NN;
    int* row_ptr = rp_all + (size_t)enc * (NN + 1);
    int* cursor = cur_all + (size_t)enc * (NN + 1);
    __shared__ int wsum[16];
    __shared__ int carry;
    int t = threadIdx.x;
    int lane = t & 63, wid = t >> 6;
    if (t == 0) carry = 0;
    __syncthreads();
    for (int base = 0; base < n; base += 4096) {
        int i0 = base + t * 4;
        int4 v = make_int4(0, 0, 0, 0);
        if (i0 + 3 < n) v = *(const int4*)(deg + i0);
        else if (i0 < n) {
            v.x = deg[i0];
            if (i0 + 1 < n) v.y = deg[i0 + 1];
            if (i0 + 2 < n) v.z = deg[i0 + 2];
        }
        int s = v.x + v.y + v.z + v.w;
        int x = s;
        #pragma unroll
        for (int d = 1; d < 64; d <<= 1) {
            int y = __shfl_up(x, d, 64);
            if (lane >= d) x += y;
        }
        if (lane == 63) wsum[wid] = x;
        __syncthreads();
        if (t == 0) {
            int run = carry;
            #pragma unroll
            for (int w = 0; w < 16; ++w) { int q = wsum[w]; wsum[w] = run; run += q; }
            carry = run;
        }
        __syncthreads();
        if (i0 < n) {
            int excl = wsum[wid] + x - s;
            int p1 = excl + v.x, p2 = p1 + v.y, p3 = p2 + v.z;
            row_ptr[i0] = excl; cursor[i0] = excl;
            if (i0 + 1 < n) { row_ptr[i0 + 1] = p1; cursor[i0 + 1] = p1; }
            if (i0 + 2 < n) { row_ptr[i0 + 2] = p2; cursor[i0 + 2] = p2; }
            if (i0 + 3 < n) { row_ptr[i0 + 3] = p3; cursor[i0 + 3] = p3; }
        }
        __syncthreads();
    }
    if (t == 0) row_ptr[n] = carry;
}

// XCD-range-partitioned scatter: blockIdx%8 selects a dst range; all blocks of
// range r land on XCD r, so csr/cursor writes for that range stay in its L2.
// Each thread handles 4 edges (E % 4 == 0, so a group never straddles the enc split).
__global__ __launch_bounds__(256)
void scatter_kernel(const int* __restrict__ s1, const int* __restrict__ d1,
                    const int* __restrict__ s2, const int* __restrict__ d2,
                    int* __restrict__ cur_all, u16* __restrict__ csr_all, int E) {
    int range = blockIdx.x & (NRANGE - 1);
    int lo = range * RN, hi = lo + RN;
    int chunk = blockIdx.x >> 3;
    int e = chunk * 1024 + threadIdx.x * 4;
    const int* s = s1; const int* d = d1; int enc = 0;
    if (e >= E) { e -= E; s = s2; d = d2; enc = 1; }
    if (e >= E) return;
    int4 dv = *(const int4*)(d + e);
    bool any = (dv.x >= lo && dv.x < hi) || (dv.y >= lo && dv.y < hi) ||
               (dv.z >= lo && dv.z < hi) || (dv.w >= lo && dv.w < hi);
    if (!any) return;
    int4 sv = *(const int4*)(s + e);
    int* cursor = cur_all + (size_t)enc * (NN + 1);
    u16* csr = csr_all + (size_t)enc * NE;
    #pragma unroll
    for (int j = 0; j < 4; ++j) {
        int dst = j == 0 ? dv.x : j == 1 ? dv.y : j == 2 ? dv.z : dv.w;
        int src = j == 0 ? sv.x : j == 1 ? sv.y : j == 2 ? sv.z : sv.w;
        if (dst >= lo && dst < hi) {
            int pos = atomicAdd(&cursor[dst], 1);
            csr[pos] = (u16)src;
        }
    }
}

// all four weight matrices: blockIdx.y = {W1a, W1b, W2a, W2b};  W [K][N] f32 -> Wt [N][K] bf16
__global__ void convw_kernel(const float* __restrict__ W1a, const float* __restrict__ W1b,
                             const float* __restrict__ W2a, const float* __restrict__ W2b,
                             u16* __restrict__ W1t_all, u16* __restrict__ W2t_all) {
    int mat = blockIdx.y;
    int idx = blockIdx.x * blockDim.x + threadIdx.x;
    const float* W; u16* Wt; int K, N;
    if (mat < 2) { W = mat ? W1b : W1a; Wt = W1t_all + (size_t)mat * 512 * 256; K = 512; N = 256; }
    else         { W = (mat == 3) ? W2b : W2a; Wt = W2t_all + (size_t)(mat - 2) * 256 * 128; K = 256; N = 128; }
    if (idx < K * N) {
        int k = idx / N, n = idx - k * N;
        Wt[(size_t)n * K + k] = f2bf_u16(W[idx]);
    }
}

// ---------------- MFMA GEMM: C = A @ Bt^T (dual-encoder via blockIdx.z) ----------------
// A: [M][K] (f32 or bf16), Bt: [N][K] bf16, C: [M][N] (bf16 or f32)
// SCALE: C[row] *= rowscale[row] (folds ns into Y).  TRIANG: z = triu(R R^T), nontemporal.

template<bool A_F32, bool OUT_BF16, bool TRIANG, bool SCALE>
__global__ __launch_bounds__(256)
void gemm_kernel(const void* __restrict__ A0_, const void* __restrict__ A1_,
                 const u16* __restrict__ Bt0, const u16* __restrict__ Bt1,
                 void* __restrict__ C0_, void* __restrict__ C1_,
                 const float* __restrict__ rs0, const float* __restrict__ rs1,
                 int M, int N, int K) {
    int enc = blockIdx.z;
    const void* A_ = enc ? A1_ : A0_;
    const u16* Bt = enc ? Bt1 : Bt0;
    void* C_ = enc ? C1_ : C0_;
    const float* rowscale = enc ? rs1 : rs0;

    int it = blockIdx.x, jt = blockIdx.y;
    int t = threadIdx.x;
    int brow = it * 128, bcol = jt * 128;
    float* Cf = (float*)C_;
    if (TRIANG && jt < it) {
        f32x4 z = {0.f, 0.f, 0.f, 0.f};
        #pragma unroll
        for (int p = 0; p < 16; ++p) {
            int idx = p * 256 + t;
            int r = idx >> 5, c4 = idx & 31;
            __builtin_nontemporal_store(z, (f32x4*)(Cf + (size_t)(brow + r) * N + bcol + c4 * 4));
        }
        return;
    }
    __shared__ u16 As[128 * 40];
    __shared__ u16 Bs[128 * 40];
    int lane = t & 63, wv = t >> 6;
    int wr = wv >> 1, wc = wv & 1;
    f32x4 acc[4][4];
    #pragma unroll
    for (int m = 0; m < 4; ++m)
        #pragma unroll
        for (int n = 0; n < 4; ++n) acc[m][n] = f32x4{0.f, 0.f, 0.f, 0.f};

    for (int k0 = 0; k0 < K; k0 += 32) {
        if (A_F32) {
            const float* A = (const float*)A_;
            #pragma unroll
            for (int p = 0; p < 4; ++p) {
                int r = p * 32 + (t >> 3), c = (t & 7) * 4;
                int gr = brow + r;
                float4 v = make_float4(0.f, 0.f, 0.f, 0.f);
                if (gr < M) v = *(const float4*)(A + (size_t)gr * K + k0 + c);
                u32 lo = (u32)f2bf_u16(v.x) | ((u32)f2bf_u16(v.y) << 16);
                u32 hi = (u32)f2bf_u16(v.z) | ((u32)f2bf_u16(v.w) << 16);
                *(uint2*)&As[r * 40 + c] = make_uint2(lo, hi);
            }
        } else {
            const u16* A = (const u16*)A_;
            #pragma unroll
            for (int p = 0; p < 2; ++p) {
                int r = p * 64 + (t >> 2), c = (t & 3) * 8;
                int gr = brow + r;
                uint4 v = make_uint4(0u, 0u, 0u, 0u);
                if (gr < M) v = *(const uint4*)(A + (size_t)gr * K + k0 + c);
                *(uint4*)&As[r * 40 + c] = v;
            }
        }
        #pragma unroll
        for (int p = 0; p < 2; ++p) {
            int r = p * 64 + (t >> 2), c = (t & 3) * 8;
            int gn = bcol + r;
            uint4 v = make_uint4(0u, 0u, 0u, 0u);
            if (gn < N) v = *(const uint4*)(Bt + (size_t)gn * K + k0 + c);
            *(uint4*)&Bs[r * 40 + c] = v;
        }
        __syncthreads();
        int kg = (lane >> 4) * 8;
        short8 av[4], bv[4];
        #pragma unroll
        for (int m = 0; m < 4; ++m)
            av[m] = *(const short8*)&As[(wr * 64 + m * 16 + (lane & 15)) * 40 + kg];
        #pragma unroll
        for (int n = 0; n < 4; ++n)
            bv[n] = *(const short8*)&Bs[(wc * 64 + n * 16 + (lane & 15)) * 40 + kg];
        #pragma unroll
        for (int m = 0; m < 4; ++m)
            #pragma unroll
            for (int n = 0; n < 4; ++n)
                acc[m][n] = __builtin_amdgcn_mfma_f32_16x16x32_bf16(av[m], bv[n], acc[m][n], 0, 0, 0);
        __syncthreads();
    }
    #pragma unroll
    for (int m = 0; m < 4; ++m) {
        #pragma unroll
        for (int n = 0; n < 4; ++n) {
            #pragma unroll
            for (int r = 0; r < 4; ++r) {
                int row = brow + wr * 64 + m * 16 + (lane >> 4) * 4 + r;
                int col = bcol + wc * 64 + n * 16 + (lane & 15);
                if (row < M && col < N) {
                    float v = acc[m][n][r];
                    if (SCALE) v *= rowscale[row];
                    if (TRIANG) {
                        if (col < row) v = 0.f;
                        __builtin_nontemporal_store(v, Cf + (size_t)row * N + col);
                    } else if (OUT_BF16) {
                        ((u16*)C_)[(size_t)row * N + col] = f2bf_u16(v);
                    } else {
                        Cf[(size_t)row * N + col] = v;
                    }
                }
            }
        }
    }
}

// ---------------- aggregation: out[d] = nd[d] * sum_{e in in(d)} Y[s] + b ----------------
// (Y pre-scaled by ns in GEMM epilogue.)  blockIdx.y = enc.  csr entries are u16.

template<int F, bool RELU, bool OUT_BF16>
__global__ __launch_bounds__(256)
void agg_kernel(const u16* __restrict__ Yall, const int* __restrict__ rp_all,
                const u16* __restrict__ csr_all, const float* __restrict__ norms,
                const float* __restrict__ bias0, const float* __restrict__ bias1,
                void* __restrict__ out_all, int n_nodes) {
    constexpr int VPL = F / 64;  // values per lane
    int enc = blockIdx.y;
    const u16* Y = Yall + (size_t)enc * n_nodes * F;
    const int* row_ptr = rp_all + (size_t)enc * (n_nodes + 1);
    const u16* csr = csr_all + (size_t)enc * NE;
    const float* nd = norms + (size_t)(2 * enc + 1) * NN;
    const float* bias = enc ? bias1 : bias0;

    int lane = threadIdx.x & 63;
    int node = blockIdx.x * 4 + (threadIdx.x >> 6);
    if (node >= n_nodes) return;
    int e0 = row_ptr[node], e1 = row_ptr[node + 1];
    float acc[VPL];
    #pragma unroll
    for (int j = 0; j < VPL; ++j) acc[j] = 0.f;
    const int off = lane * VPL;

    int e = e0;
    // peel to 16B alignment of csr+e (8 u16 entries)
    for (; e < e1 && (e & 7) != 0; ++e) {
        int s = csr[e];
        if (VPL == 4) {
            uint2 d = *(const uint2*)(Y + (size_t)s * F + off);
            acc[0] += bfu(d.x & 0xffffu); acc[1] += bfu(d.x >> 16);
            acc[2] += bfu(d.y & 0xffffu); acc[3] += bfu(d.y >> 16);
        } else {
            u32 d = *(const u32*)(Y + (size_t)s * F + off);
            acc[0] += bfu(d & 0xffffu); acc[1] += bfu(d >> 16);
        }
    }
    for (; e + 8 <= e1; e += 8) {
        uint4 iv = *(const uint4*)(csr + e);
        int s0 = iv.x & 0xffff, s1 = iv.x >> 16;
        int s2 = iv.y & 0xffff, s3 = iv.y >> 16;
        int s4 = iv.z & 0xffff, s5 = iv.z >> 16;
        int s6 = iv.w & 0xffff, s7 = iv.w >> 16;
        if (VPL == 4) {
            uint2 d0 = *(const uint2*)(Y + (size_t)s0 * F + off);
            uint2 d1 = *(const uint2*)(Y + (size_t)s1 * F + off);
            uint2 d2 = *(const uint2*)(Y + (size_t)s2 * F + off);
            uint2 d3 = *(const uint2*)(Y + (size_t)s3 * F + off);
            uint2 d4 = *(const uint2*)(Y + (size_t)s4 * F + off);
            uint2 d5 = *(const uint2*)(Y + (size_t)s5 * F + off);
            uint2 d6 = *(const uint2*)(Y + (size_t)s6 * F + off);
            uint2 d7 = *(const uint2*)(Y + (size_t)s7 * F + off);
            acc[0] += bfu(d0.x & 0xffffu); acc[1] += bfu(d0.x >> 16); acc[2] += bfu(d0.y & 0xffffu); acc[3] += bfu(d0.y >> 16);
            acc[0] += bfu(d1.x & 0xffffu); acc[1] += bfu(d1.x >> 16); acc[2] += bfu(d1.y & 0xffffu); acc[3] += bfu(d1.y >> 16);
            acc[0] += bfu(d2.x & 0xffffu); acc[1] += bfu(d2.x >> 16); acc[2] += bfu(d2.y & 0xffffu); acc[3] += bfu(d2.y >> 16);
            acc[0] += bfu(d3.x & 0xffffu); acc[1] += bfu(d3.x >> 16); acc[2] += bfu(d3.y & 0xffffu); acc[3] += bfu(d3.y >> 16);
            acc[0] += bfu(d4.x & 0xffffu); acc[1] += bfu(d4.x >> 16); acc[2] += bfu(d4.y & 0xffffu); acc[3] += bfu(d4.y >> 16);
            acc[0] += bfu(d5.x & 0xffffu); acc[1] += bfu(d5.x >> 16); acc[2] += bfu(d5.y & 0xffffu); acc[3] += bfu(d5.y >> 16);
            acc[0] += bfu(d6.x & 0xffffu); acc[1] += bfu(d6.x >> 16); acc[2] += bfu(d6.y & 0xffffu); acc[3] += bfu(d6.y >> 16);
            acc[0] += bfu(d7.x & 0xffffu); acc[1] += bfu(d7.x >> 16); acc[2] += bfu(d7.y & 0xffffu); acc[3] += bfu(d7.y >> 16);
        } else {
            u32 d0 = *(const u32*)(Y + (size_t)s0 * F + off);
            u32 d1 = *(const u32*)(Y + (size_t)s1 * F + off);
            u32 d2 = *(const u32*)(Y + (size_t)s2 * F + off);
            u32 d3 = *(const u32*)(Y + (size_t)s3 * F + off);
            u32 d4 = *(const u32*)(Y + (size_t)s4 * F + off);
            u32 d5 = *(const u32*)(Y + (size_t)s5 * F + off);
            u32 d6 = *(const u32*)(Y + (size_t)s6 * F + off);
            u32 d7 = *(const u32*)(Y + (size_t)s7 * F + off);
            acc[0] += bfu(d0 & 0xffffu); acc[1] += bfu(d0 >> 16);
            acc[0] += bfu(d1 & 0xffffu); acc[1] += bfu(d1 >> 16);
            acc[0] += bfu(d2 & 0xffffu); acc[1] += bfu(d2 >> 16);
            acc[0] += bfu(d3 & 0xffffu); acc[1] += bfu(d3 >> 16);
            acc[0] += bfu(d4 & 0xffffu); acc[1] += bfu(d4 >> 16);
            acc[0] += bfu(d5 & 0xffffu); acc[1] += bfu(d5 >> 16);
            acc[0] += bfu(d6 & 0xffffu); acc[1] += bfu(d6 >> 16);
            acc[0] += bfu(d7 & 0xffffu); acc[1] += bfu(d7 >> 16);
        }
    }
    for (; e < e1; ++e) {
        int s = csr[e];
        if (VPL == 4) {
            uint2 d = *(const uint2*)(Y + (size_t)s * F + off);
            acc[0] += bfu(d.x & 0xffffu); acc[1] += bfu(d.x >> 16);
            acc[2] += bfu(d.y & 0xffffu); acc[3] += bfu(d.y >> 16);
        } else {
            u32 d = *(const u32*)(Y + (size_t)s * F + off);
            acc[0] += bfu(d & 0xffffu); acc[1] += bfu(d >> 16);
        }
    }

    float ndv = nd[node];
    #pragma unroll
    for (int j = 0; j < VPL; ++j) {
        float o = acc[j] * ndv + bias[off + j];
        if (RELU) o = fmaxf(o, 0.f);
        if (OUT_BF16) ((u16*)out_all)[(size_t)enc * n_nodes * F + (size_t)node * F + off + j] = f2bf_u16(o);
        else ((float*)out_all)[(size_t)enc * n_nodes * F + (size_t)node * F + off + j] = o;
    }
}

// ---------------- normalize + build R = [ (a+b)/2 , (a-b)/(2*sqrt(3)) ] ----------------

__global__ __launch_bounds__(256)
void build_r_kernel(const float* __restrict__ H2a, const float* __restrict__ H2b,
                    const int* __restrict__ index, u16* __restrict__ R) {
    int lane = threadIdx.x & 63;
    int row = blockIdx.x * 4 + (threadIdx.x >> 6);
    int g = index[row];
    float2 a = *(const float2*)(H2a + (size_t)g * 128 + lane * 2);
    float2 b = *(const float2*)(H2b + (size_t)g * 128 + lane * 2);
    float sa = a.x * a.x + a.y * a.y;
    float sb = b.x * b.x + b.y * b.y;
    #pragma unroll
    for (int d = 1; d < 64; d <<= 1) {
        sa += __shfl_xor(sa, d, 64);
        sb += __shfl_xor(sb, d, 64);
    }
    float inva = 1.f / fmaxf(sqrtf(sa), 1e-12f);
    float invb = 1.f / fmaxf(sqrtf(sb), 1e-12f);
    float ax = a.x * inva, ay = a.y * inva;
    float bx = b.x * invb, by = b.y * invb;
    const float c2 = 0.5f, c3 = 0.28867513459481287f;  // 1/(2*sqrt(3))
    u16* Rp = R + (size_t)row * 256;
    Rp[lane * 2]           = f2bf_u16((ax + bx) * c2);
    Rp[lane * 2 + 1]       = f2bf_u16((ay + by) * c2);
    Rp[128 + lane * 2]     = f2bf_u16((ax - bx) * c3);
    Rp[128 + lane * 2 + 1] = f2bf_u16((ay - by) * c3);
}

// ---------------- launch ----------------

extern "C" void kernel_launch(void* const* d_in, const int* in_sizes, int n_in,
                              void* d_out, int out_size, void* d_ws, size_t ws_size,
                              hipStream_t stream) {
    (void)in_sizes; (void)n_in; (void)out_size; (void)ws_size;
    const float* raw[2]  = {(const float*)d_in[0], (const float*)d_in[1]};
    const int* src1 = (const int*)d_in[2], *dst1 = (const int*)d_in[3];
    const int* src2 = (const int*)d_in[4], *dst2 = (const int*)d_in[5];
    const int* index = (const int*)d_in[6];
    const float* W1[2] = {(const float*)d_in[7],  (const float*)d_in[11]};
    const float* b1[2] = {(const float*)d_in[8],  (const float*)d_in[12]};
    const float* W2[2] = {(const float*)d_in[9],  (const float*)d_in[13]};
    const float* b2[2] = {(const float*)d_in[10], (const float*)d_in[14]};

    char* p = (char*)d_ws;
    auto alloc = [&](size_t bytes) -> char* {
        char* r = p;
        p += (bytes + 255) & ~(size_t)255;
        return r;
    };
    int*   deg_all = (int*)alloc((size_t)4 * NN * 4);
    float* norms   = (float*)alloc((size_t)4 * NN * 4);
    int*   rp_all  = (int*)alloc((size_t)2 * (NN + 1) * 4);
    int*   cur_all = (int*)alloc((size_t)2 * (NN + 1) * 4);
    u16*   csr_all = (u16*)alloc((size_t)2 * NE * 2);
    u16*   W1t     = (u16*)alloc((size_t)2 * 512 * 256 * 2);
    u16*   W2t     = (u16*)alloc((size_t)2 * 256 * 128 * 2);
    u16*   Y1      = (u16*)alloc((size_t)2 * NN * 256 * 2);
    u16*   H1      = (u16*)alloc((size_t)2 * NN * 256 * 2);
    u16*   Y2      = (u16*)alloc((size_t)2 * NN * 128 * 2);
    float* H2      = (float*)alloc((size_t)2 * NN * 128 * 4);
    u16*   R       = (u16*)alloc((size_t)NIDX * 256 * 2);

    const int MT = (NN + 127) / 128;  // 391 row tiles

    hipMemsetAsync(deg_all, 0, (size_t)4 * NN * 4, stream);
    hist_kernel<<<(2 * NE + 255) / 256, 256, 0, stream>>>(src1, dst1, src2, dst2, deg_all, NE);
    norm_kernel<<<(4 * NN + 255) / 256, 256, 0, stream>>>(deg_all, norms, 4 * NN);
    scan_kernel<<<2, 1024, 0, stream>>>(deg_all, rp_all, cur_all, NN);
    // 2E/1024 chunks x 8 ranges, range = blockIdx%8 -> XCD-local csr writes
    scatter_kernel<<<(2 * NE / 1024) * NRANGE, 256, 0, stream>>>(
        src1, dst1, src2, dst2, cur_all, csr_all, NE);
    convw_kernel<<<dim3((512 * 256 + 255) / 256, 4), 256, 0, stream>>>(W1[0], W1[1], W2[0], W2[1], W1t, W2t);

    // Y1 = (raw @ W1) * ns[row]   (both encoders; f32 A converted on the fly)
    gemm_kernel<true, true, false, true><<<dim3(MT, 2, 2), 256, 0, stream>>>(
        raw[0], raw[1], W1t, W1t + (size_t)512 * 256, Y1, Y1 + (size_t)NN * 256,
        norms, norms + (size_t)2 * NN, NN, 256, 512);
    // H1 = relu(nd * agg(Y1) + b1), bf16
    agg_kernel<256, true, true><<<dim3((NN + 3) / 4, 2), 256, 0, stream>>>(
        Y1, rp_all, csr_all, norms, b1[0], b1[1], H1, NN);
    // Y2 = (H1 @ W2) * ns[row]
    gemm_kernel<false, true, false, true><<<dim3(MT, 1, 2), 256, 0, stream>>>(
        H1, H1 + (size_t)NN * 256, W2t, W2t + (size_t)256 * 128, Y2, Y2 + (size_t)NN * 128,
        norms, norms + (size_t)2 * NN, NN, 128, 256);
    // H2 = nd * agg(Y2) + b2, f32
    agg_kernel<128, false, false><<<dim3((NN + 3) / 4, 2), 256, 0, stream>>>(
        Y2, rp_all, csr_all, norms, b2[0], b2[1], H2, NN);

    // R = [ (c1n+c2n)/2 , (c1n-c2n)/(2*sqrt(3)) ]  (8192 x 256, bf16)
    build_r_kernel<<<NIDX / 4, 256, 0, stream>>>(H2, H2 + (size_t)NN * 128, index, R);
    // z = triu(R @ R^T), nontemporal f32 output
    gemm_kernel<false, false, true, false><<<dim3(64, 64, 1), 256, 0, stream>>>(
        R, R, R, R, (float*)d_out, (float*)d_out, nullptr, nullptr, NIDX, NIDX, 256);
}

// Round 5
// 834.632 us; speedup vs baseline: 1.8501x; 1.2449x over previous
//
#include <hip/hip_runtime.h>
#include <hip/hip_bf16.h>

using u16 = unsigned short;
using u32 = unsigned int;

typedef __attribute__((ext_vector_type(8))) short short8;
typedef __attribute__((ext_vector_type(4))) float f32x4;

__device__ __forceinline__ u16 f2bf_u16(float f) {
    __hip_bfloat16 h = __float2bfloat16(f);
    return __builtin_bit_cast(u16, h);
}
__device__ __forceinline__ float bfu(u32 u) { return __uint_as_float(u << 16); }

static constexpr int NN = 50000;
static constexpr int NE = 1600000;
static constexpr int NIDX = 8192;
static constexpr int NRANGE = 8;              // scatter ranges (XCD-local csr writes)
static constexpr int RN = NN / NRANGE;        // 6250 nodes per range
static constexpr int HCHUNK = 32;             // hist edge-chunks per range

// deg_all / norms layout: [enc*2+0] = out(src) arrays, [enc*2+1] = in(dst) arrays, each NN.

// ---------------- histogram: LDS-privatized partials, no global atomics ----------------
// grid.x = NRANGE * HCHUNK (range = blockIdx.x & 7, chunk = blockIdx.x >> 3), grid.y = enc.
// partial layout: [enc][hist][chunk][NN], hist 0 = out(src), 1 = in(dst).

__global__ __launch_bounds__(256)
void hist_kernel(const int* __restrict__ s1, const int* __restrict__ d1,
                 const int* __restrict__ s2, const int* __restrict__ d2,
                 int* __restrict__ partial, int E) {
    __shared__ int h_out[RN];
    __shared__ int h_in[RN];
    int enc = blockIdx.y;
    int range = blockIdx.x & (NRANGE - 1);
    int chunk = blockIdx.x >> 3;
    const int* s = enc ? s2 : s1;
    const int* d = enc ? d2 : d1;
    int lo = range * RN;
    for (int i = threadIdx.x; i < RN; i += 256) { h_out[i] = 0; h_in[i] = 0; }
    __syncthreads();
    int per_chunk = E / HCHUNK;            // 50000, divisible by 4
    int e0 = chunk * per_chunk, e1 = e0 + per_chunk;
    for (int e = e0 + threadIdx.x * 4; e < e1; e += 256 * 4) {
        int4 sv = *(const int4*)(s + e);
        int4 dv = *(const int4*)(d + e);
        u32 a0 = (u32)(sv.x - lo), a1 = (u32)(sv.y - lo), a2 = (u32)(sv.z - lo), a3 = (u32)(sv.w - lo);
        u32 b0 = (u32)(dv.x - lo), b1 = (u32)(dv.y - lo), b2 = (u32)(dv.z - lo), b3 = (u32)(dv.w - lo);
        if (a0 < (u32)RN) atomicAdd(&h_out[a0], 1);
        if (a1 < (u32)RN) atomicAdd(&h_out[a1], 1);
        if (a2 < (u32)RN) atomicAdd(&h_out[a2], 1);
        if (a3 < (u32)RN) atomicAdd(&h_out[a3], 1);
        if (b0 < (u32)RN) atomicAdd(&h_in[b0], 1);
        if (b1 < (u32)RN) atomicAdd(&h_in[b1], 1);
        if (b2 < (u32)RN) atomicAdd(&h_in[b2], 1);
        if (b3 < (u32)RN) atomicAdd(&h_in[b3], 1);
    }
    __syncthreads();
    int* p_out = partial + ((size_t)(enc * 2 + 0) * HCHUNK + chunk) * NN + lo;
    int* p_in  = partial + ((size_t)(enc * 2 + 1) * HCHUNK + chunk) * NN + lo;
    for (int i = threadIdx.x; i < RN; i += 256) { p_out[i] = h_out[i]; p_in[i] = h_in[i]; }
}

__global__ void reduce_hist_kernel(const int* __restrict__ partial, int* __restrict__ deg_all) {
    int i = blockIdx.x * blockDim.x + threadIdx.x;   // over 4*NN
    if (i >= 4 * NN) return;
    int which = i / NN;
    int node = i - which * NN;
    const int* p = partial + (size_t)which * HCHUNK * NN + node;
    int sum = 0;
    #pragma unroll
    for (int c = 0; c < HCHUNK; ++c) sum += p[(size_t)c * NN];
    deg_all[i] = sum;
}

__global__ void norm_kernel(const int* __restrict__ deg_all, float* __restrict__ norms, int n4) {
    int i = blockIdx.x * blockDim.x + threadIdx.x;
    if (i < n4) norms[i] = rsqrtf(fmaxf((float)deg_all[i], 1.f));
}

// one block per encoder (blockIdx.x = enc); exclusive scan of deg_in -> row_ptr, cursor
__global__ __launch_bounds__(1024)
void scan_kernel(const int* __restrict__ deg_all, int* __restrict__ rp_all,
                 int* __restrict__ cur_all, int n) {
    int enc = blockIdx.x;
    const int* deg = deg_all + (size_t)(2 * enc + 1) * NN;
    int* row_ptr = rp_all + (size_t)enc * (NN + 1);
    int* cursor = cur_all + (size_t)enc * (NN + 1);
    __shared__ int wsum[16];
    __shared__ int carry;
    int t = threadIdx.x;
    int lane = t & 63, wid = t >> 6;
    if (t == 0) carry = 0;
    __syncthreads();
    for (int base = 0; base < n; base += 4096) {
        int i0 = base + t * 4;
        int4 v = make_int4(0, 0, 0, 0);
        if (i0 + 3 < n) v = *(const int4*)(deg + i0);
        else if (i0 < n) {
            v.x = deg[i0];
            if (i0 + 1 < n) v.y = deg[i0 + 1];
            if (i0 + 2 < n) v.z = deg[i0 + 2];
        }
        int s = v.x + v.y + v.z + v.w;
        int x = s;
        #pragma unroll
        for (int d = 1; d < 64; d <<= 1) {
            int y = __shfl_up(x, d, 64);
            if (lane >= d) x += y;
        }
        if (lane == 63) wsum[wid] = x;
        __syncthreads();
        if (t == 0) {
            int run = carry;
            #pragma unroll
            for (int w = 0; w < 16; ++w) { int q = wsum[w]; wsum[w] = run; run += q; }
            carry = run;
        }
        __syncthreads();
        if (i0 < n) {
            int excl = wsum[wid] + x - s;
            int p1 = excl + v.x, p2 = p1 + v.y, p3 = p2 + v.z;
            row_ptr[i0] = excl; cursor[i0] = excl;
            if (i0 + 1 < n) { row_ptr[i0 + 1] = p1; cursor[i0 + 1] = p1; }
            if (i0 + 2 < n) { row_ptr[i0 + 2] = p2; cursor[i0 + 2] = p2; }
            if (i0 + 3 < n) { row_ptr[i0 + 3] = p3; cursor[i0 + 3] = p3; }
        }
        __syncthreads();
    }
    if (t == 0) row_ptr[n] = carry;
}

// XCD-range-partitioned scatter: blockIdx%8 selects a dst range; all blocks of
// range r land on XCD r, so csr/cursor writes for that range stay in its L2.
__global__ __launch_bounds__(256)
void scatter_kernel(const int* __restrict__ s1, const int* __restrict__ d1,
                    const int* __restrict__ s2, const int* __restrict__ d2,
                    int* __restrict__ cur_all, u16* __restrict__ csr_all, int E) {
    int range = blockIdx.x & (NRANGE - 1);
    int lo = range * RN, hi = lo + RN;
    int chunk = blockIdx.x >> 3;
    int e = chunk * 1024 + threadIdx.x * 4;
    const int* s = s1; const int* d = d1; int enc = 0;
    if (e >= E) { e -= E; s = s2; d = d2; enc = 1; }
    if (e >= E) return;
    int4 dv = *(const int4*)(d + e);
    bool any = (dv.x >= lo && dv.x < hi) || (dv.y >= lo && dv.y < hi) ||
               (dv.z >= lo && dv.z < hi) || (dv.w >= lo && dv.w < hi);
    if (!any) return;
    int4 sv = *(const int4*)(s + e);
    int* cursor = cur_all + (size_t)enc * (NN + 1);
    u16* csr = csr_all + (size_t)enc * NE;
    #pragma unroll
    for (int j = 0; j < 4; ++j) {
        int dst = j == 0 ? dv.x : j == 1 ? dv.y : j == 2 ? dv.z : dv.w;
        int src = j == 0 ? sv.x : j == 1 ? sv.y : j == 2 ? sv.z : sv.w;
        if (dst >= lo && dst < hi) {
            int pos = atomicAdd(&cursor[dst], 1);
            csr[pos] = (u16)src;
        }
    }
}

// all four weight matrices: blockIdx.y = {W1a, W1b, W2a, W2b};  W [K][N] f32 -> Wt [N][K] bf16
__global__ void convw_kernel(const float* __restrict__ W1a, const float* __restrict__ W1b,
                             const float* __restrict__ W2a, const float* __restrict__ W2b,
                             u16* __restrict__ W1t_all, u16* __restrict__ W2t_all) {
    int mat = blockIdx.y;
    int idx = blockIdx.x * blockDim.x + threadIdx.x;
    const float* W; u16* Wt; int K, N;
    if (mat < 2) { W = mat ? W1b : W1a; Wt = W1t_all + (size_t)mat * 512 * 256; K = 512; N = 256; }
    else         { W = (mat == 3) ? W2b : W2a; Wt = W2t_all + (size_t)(mat - 2) * 256 * 128; K = 256; N = 128; }
    if (idx < K * N) {
        int k = idx / N, n = idx - k * N;
        Wt[(size_t)n * K + k] = f2bf_u16(W[idx]);
    }
}

// ---------------- MFMA GEMM: C = A @ Bt^T (dual-encoder via blockIdx.z) ----------------
// A: [M][K] (f32 or bf16), Bt: [N][K] bf16, C: [M][N] (bf16 or f32)
// SCALE: C[row] *= rowscale[row] (folds ns into Y).  TRIANG: z = triu(R R^T), nontemporal.

template<bool A_F32, bool OUT_BF16, bool TRIANG, bool SCALE>
__global__ __launch_bounds__(256)
void gemm_kernel(const void* __restrict__ A0_, const void* __restrict__ A1_,
                 const u16* __restrict__ Bt0, const u16* __restrict__ Bt1,
                 void* __restrict__ C0_, void* __restrict__ C1_,
                 const float* __restrict__ rs0, const float* __restrict__ rs1,
                 int M, int N, int K) {
    int enc = blockIdx.z;
    const void* A_ = enc ? A1_ : A0_;
    const u16* Bt = enc ? Bt1 : Bt0;
    void* C_ = enc ? C1_ : C0_;
    const float* rowscale = enc ? rs1 : rs0;

    int it = blockIdx.x, jt = blockIdx.y;
    int t = threadIdx.x;
    int brow = it * 128, bcol = jt * 128;
    float* Cf = (float*)C_;
    if (TRIANG && jt < it) {
        f32x4 z = {0.f, 0.f, 0.f, 0.f};
        #pragma unroll
        for (int p = 0; p < 16; ++p) {
            int idx = p * 256 + t;
            int r = idx >> 5, c4 = idx & 31;
            __builtin_nontemporal_store(z, (f32x4*)(Cf + (size_t)(brow + r) * N + bcol + c4 * 4));
        }
        return;
    }
    __shared__ u16 As[128 * 40];
    __shared__ u16 Bs[128 * 40];
    int lane = t & 63, wv = t >> 6;
    int wr = wv >> 1, wc = wv & 1;
    f32x4 acc[4][4];
    #pragma unroll
    for (int m = 0; m < 4; ++m)
        #pragma unroll
        for (int n = 0; n < 4; ++n) acc[m][n] = f32x4{0.f, 0.f, 0.f, 0.f};

    for (int k0 = 0; k0 < K; k0 += 32) {
        if (A_F32) {
            const float* A = (const float*)A_;
            #pragma unroll
            for (int p = 0; p < 4; ++p) {
                int r = p * 32 + (t >> 3), c = (t & 7) * 4;
                int gr = brow + r;
                float4 v = make_float4(0.f, 0.f, 0.f, 0.f);
                if (gr < M) v = *(const float4*)(A + (size_t)gr * K + k0 + c);
                u32 lo = (u32)f2bf_u16(v.x) | ((u32)f2bf_u16(v.y) << 16);
                u32 hi = (u32)f2bf_u16(v.z) | ((u32)f2bf_u16(v.w) << 16);
                *(uint2*)&As[r * 40 + c] = make_uint2(lo, hi);
            }
        } else {
            const u16* A = (const u16*)A_;
            #pragma unroll
            for (int p = 0; p < 2; ++p) {
                int r = p * 64 + (t >> 2), c = (t & 3) * 8;
                int gr = brow + r;
                uint4 v = make_uint4(0u, 0u, 0u, 0u);
                if (gr < M) v = *(const uint4*)(A + (size_t)gr * K + k0 + c);
                *(uint4*)&As[r * 40 + c] = v;
            }
        }
        #pragma unroll
        for (int p = 0; p < 2; ++p) {
            int r = p * 64 + (t >> 2), c = (t & 3) * 8;
            int gn = bcol + r;
            uint4 v = make_uint4(0u, 0u, 0u, 0u);
            if (gn < N) v = *(const uint4*)(Bt + (size_t)gn * K + k0 + c);
            *(uint4*)&Bs[r * 40 + c] = v;
        }
        __syncthreads();
        int kg = (lane >> 4) * 8;
        short8 av[4], bv[4];
        #pragma unroll
        for (int m = 0; m < 4; ++m)
            av[m] = *(const short8*)&As[(wr * 64 + m * 16 + (lane & 15)) * 40 + kg];
        #pragma unroll
        for (int n = 0; n < 4; ++n)
            bv[n] = *(const short8*)&Bs[(wc * 64 + n * 16 + (lane & 15)) * 40 + kg];
        #pragma unroll
        for (int m = 0; m < 4; ++m)
            #pragma unroll
            for (int n = 0; n < 4; ++n)
                acc[m][n] = __builtin_amdgcn_mfma_f32_16x16x32_bf16(av[m], bv[n], acc[m][n], 0, 0, 0);
        __syncthreads();
    }
    #pragma unroll
    for (int m = 0; m < 4; ++m) {
        #pragma unroll
        for (int n = 0; n < 4; ++n) {
            #pragma unroll
            for (int r = 0; r < 4; ++r) {
                int row = brow + wr * 64 + m * 16 + (lane >> 4) * 4 + r;
                int col = bcol + wc * 64 + n * 16 + (lane & 15);
                if (row < M && col < N) {
                    float v = acc[m][n][r];
                    if (SCALE) v *= rowscale[row];
                    if (TRIANG) {
                        if (col < row) v = 0.f;
                        __builtin_nontemporal_store(v, Cf + (size_t)row * N + col);
                    } else if (OUT_BF16) {
                        ((u16*)C_)[(size_t)row * N + col] = f2bf_u16(v);
                    } else {
                        Cf[(size_t)row * N + col] = v;
                    }
                }
            }
        }
    }
}

// ---------------- aggregation: out[d] = nd[d] * sum_{e in in(d)} Y[s] + b ----------------
// (Y pre-scaled by ns in GEMM epilogue.)  blockIdx.y = enc.  csr entries are u16.

template<int F, bool RELU, bool OUT_BF16>
__global__ __launch_bounds__(256)
void agg_kernel(const u16* __restrict__ Yall, const int* __restrict__ rp_all,
                const u16* __restrict__ csr_all, const float* __restrict__ norms,
                const float* __restrict__ bias0, const float* __restrict__ bias1,
                void* __restrict__ out_all, int n_nodes) {
    constexpr int VPL = F / 64;  // values per lane
    int enc = blockIdx.y;
    const u16* Y = Yall + (size_t)enc * n_nodes * F;
    const int* row_ptr = rp_all + (size_t)enc * (n_nodes + 1);
    const u16* csr = csr_all + (size_t)enc * NE;
    const float* nd = norms + (size_t)(2 * enc + 1) * NN;
    const float* bias = enc ? bias1 : bias0;

    int lane = threadIdx.x & 63;
    int node = blockIdx.x * 4 + (threadIdx.x >> 6);
    if (node >= n_nodes) return;
    int e0 = row_ptr[node], e1 = row_ptr[node + 1];
    float acc[VPL];
    #pragma unroll
    for (int j = 0; j < VPL; ++j) acc[j] = 0.f;
    const int off = lane * VPL;

    int e = e0;
    // peel to 16B alignment of csr+e (8 u16 entries)
    for (; e < e1 && (e & 7) != 0; ++e) {
        int s = csr[e];
        if (VPL == 4) {
            uint2 d = *(const uint2*)(Y + (size_t)s * F + off);
            acc[0] += bfu(d.x & 0xffffu); acc[1] += bfu(d.x >> 16);
            acc[2] += bfu(d.y & 0xffffu); acc[3] += bfu(d.y >> 16);
        } else {
            u32 d = *(const u32*)(Y + (size_t)s * F + off);
            acc[0] += bfu(d & 0xffffu); acc[1] += bfu(d >> 16);
        }
    }
    for (; e + 8 <= e1; e += 8) {
        uint4 iv = *(const uint4*)(csr + e);
        int s0 = iv.x & 0xffff, s1 = iv.x >> 16;
        int s2 = iv.y & 0xffff, s3 = iv.y >> 16;
        int s4 = iv.z & 0xffff, s5 = iv.z >> 16;
        int s6 = iv.w & 0xffff, s7 = iv.w >> 16;
        if (VPL == 4) {
            uint2 d0 = *(const uint2*)(Y + (size_t)s0 * F + off);
            uint2 d1 = *(const uint2*)(Y + (size_t)s1 * F + off);
            uint2 d2 = *(const uint2*)(Y + (size_t)s2 * F + off);
            uint2 d3 = *(const uint2*)(Y + (size_t)s3 * F + off);
            uint2 d4 = *(const uint2*)(Y + (size_t)s4 * F + off);
            uint2 d5 = *(const uint2*)(Y + (size_t)s5 * F + off);
            uint2 d6 = *(const uint2*)(Y + (size_t)s6 * F + off);
            uint2 d7 = *(const uint2*)(Y + (size_t)s7 * F + off);
            acc[0] += bfu(d0.x & 0xffffu); acc[1] += bfu(d0.x >> 16); acc[2] += bfu(d0.y & 0xffffu); acc[3] += bfu(d0.y >> 16);
            acc[0] += bfu(d1.x & 0xffffu); acc[1] += bfu(d1.x >> 16); acc[2] += bfu(d1.y & 0xffffu); acc[3] += bfu(d1.y >> 16);
            acc[0] += bfu(d2.x & 0xffffu); acc[1] += bfu(d2.x >> 16); acc[2] += bfu(d2.y & 0xffffu); acc[3] += bfu(d2.y >> 16);
            acc[0] += bfu(d3.x & 0xffffu); acc[1] += bfu(d3.x >> 16); acc[2] += bfu(d3.y & 0xffffu); acc[3] += bfu(d3.y >> 16);
            acc[0] += bfu(d4.x & 0xffffu); acc[1] += bfu(d4.x >> 16); acc[2] += bfu(d4.y & 0xffffu); acc[3] += bfu(d4.y >> 16);
            acc[0] += bfu(d5.x & 0xffffu); acc[1] += bfu(d5.x >> 16); acc[2] += bfu(d5.y & 0xffffu); acc[3] += bfu(d5.y >> 16);
            acc[0] += bfu(d6.x & 0xffffu); acc[1] += bfu(d6.x >> 16); acc[2] += bfu(d6.y & 0xffffu); acc[3] += bfu(d6.y >> 16);
            acc[0] += bfu(d7.x & 0xffffu); acc[1] += bfu(d7.x >> 16); acc[2] += bfu(d7.y & 0xffffu); acc[3] += bfu(d7.y >> 16);
        } else {
            u32 d0 = *(const u32*)(Y + (size_t)s0 * F + off);
            u32 d1 = *(const u32*)(Y + (size_t)s1 * F + off);
            u32 d2 = *(const u32*)(Y + (size_t)s2 * F + off);
            u32 d3 = *(const u32*)(Y + (size_t)s3 * F + off);
            u32 d4 = *(const u32*)(Y + (size_t)s4 * F + off);
            u32 d5 = *(const u32*)(Y + (size_t)s5 * F + off);
            u32 d6 = *(const u32*)(Y + (size_t)s6 * F + off);
            u32 d7 = *(const u32*)(Y + (size_t)s7 * F + off);
            acc[0] += bfu(d0 & 0xffffu); acc[1] += bfu(d0 >> 16);
            acc[0] += bfu(d1 & 0xffffu); acc[1] += bfu(d1 >> 16);
            acc[0] += bfu(d2 & 0xffffu); acc[1] += bfu(d2 >> 16);
            acc[0] += bfu(d3 & 0xffffu); acc[1] += bfu(d3 >> 16);
            acc[0] += bfu(d4 & 0xffffu); acc[1] += bfu(d4 >> 16);
            acc[0] += bfu(d5 & 0xffffu); acc[1] += bfu(d5 >> 16);
            acc[0] += bfu(d6 & 0xffffu); acc[1] += bfu(d6 >> 16);
            acc[0] += bfu(d7 & 0xffffu); acc[1] += bfu(d7 >> 16);
        }
    }
    for (; e < e1; ++e) {
        int s = csr[e];
        if (VPL == 4) {
            uint2 d = *(const uint2*)(Y + (size_t)s * F + off);
            acc[0] += bfu(d.x & 0xffffu); acc[1] += bfu(d.x >> 16);
            acc[2] += bfu(d.y & 0xffffu); acc[3] += bfu(d.y >> 16);
        } else {
            u32 d = *(const u32*)(Y + (size_t)s * F + off);
            acc[0] += bfu(d & 0xffffu); acc[1] += bfu(d >> 16);
        }
    }

    float ndv = nd[node];
    #pragma unroll
    for (int j = 0; j < VPL; ++j) {
        float o = acc[j] * ndv + bias[off + j];
        if (RELU) o = fmaxf(o, 0.f);
        if (OUT_BF16) ((u16*)out_all)[(size_t)enc * n_nodes * F + (size_t)node * F + off + j] = f2bf_u16(o);
        else ((float*)out_all)[(size_t)enc * n_nodes * F + (size_t)node * F + off + j] = o;
    }
}

// ---------------- normalize + build R = [ (a+b)/2 , (a-b)/(2*sqrt(3)) ] ----------------

__global__ __launch_bounds__(256)
void build_r_kernel(const float* __restrict__ H2a, const float* __restrict__ H2b,
                    const int* __restrict__ index, u16* __restrict__ R) {
    int lane = threadIdx.x & 63;
    int row = blockIdx.x * 4 + (threadIdx.x >> 6);
    int g = index[row];
    float2 a = *(const float2*)(H2a + (size_t)g * 128 + lane * 2);
    float2 b = *(const float2*)(H2b + (size_t)g * 128 + lane * 2);
    float sa = a.x * a.x + a.y * a.y;
    float sb = b.x * b.x + b.y * b.y;
    #pragma unroll
    for (int d = 1; d < 64; d <<= 1) {
        sa += __shfl_xor(sa, d, 64);
        sb += __shfl_xor(sb, d, 64);
    }
    float inva = 1.f / fmaxf(sqrtf(sa), 1e-12f);
    float invb = 1.f / fmaxf(sqrtf(sb), 1e-12f);
    float ax = a.x * inva, ay = a.y * inva;
    float bx = b.x * invb, by = b.y * invb;
    const float c2 = 0.5f, c3 = 0.28867513459481287f;  // 1/(2*sqrt(3))
    u16* Rp = R + (size_t)row * 256;
    Rp[lane * 2]           = f2bf_u16((ax + bx) * c2);
    Rp[lane * 2 + 1]       = f2bf_u16((ay + by) * c2);
    Rp[128 + lane * 2]     = f2bf_u16((ax - bx) * c3);
    Rp[128 + lane * 2 + 1] = f2bf_u16((ay - by) * c3);
}

// ---------------- launch ----------------

extern "C" void kernel_launch(void* const* d_in, const int* in_sizes, int n_in,
                              void* d_out, int out_size, void* d_ws, size_t ws_size,
                              hipStream_t stream) {
    (void)in_sizes; (void)n_in; (void)out_size; (void)ws_size;
    const float* raw[2]  = {(const float*)d_in[0], (const float*)d_in[1]};
    const int* src1 = (const int*)d_in[2], *dst1 = (const int*)d_in[3];
    const int* src2 = (const int*)d_in[4], *dst2 = (const int*)d_in[5];
    const int* index = (const int*)d_in[6];
    const float* W1[2] = {(const float*)d_in[7],  (const float*)d_in[11]};
    const float* b1[2] = {(const float*)d_in[8],  (const float*)d_in[12]};
    const float* W2[2] = {(const float*)d_in[9],  (const float*)d_in[13]};
    const float* b2[2] = {(const float*)d_in[10], (const float*)d_in[14]};

    char* p = (char*)d_ws;
    auto alloc = [&](size_t bytes) -> char* {
        char* r = p;
        p += (bytes + 255) & ~(size_t)255;
        return r;
    };
    int*   deg_all = (int*)alloc((size_t)4 * NN * 4);
    float* norms   = (float*)alloc((size_t)4 * NN * 4);
    int*   rp_all  = (int*)alloc((size_t)2 * (NN + 1) * 4);
    int*   cur_all = (int*)alloc((size_t)2 * (NN + 1) * 4);
    u16*   csr_all = (u16*)alloc((size_t)2 * NE * 2);
    u16*   W1t     = (u16*)alloc((size_t)2 * 512 * 256 * 2);
    u16*   W2t     = (u16*)alloc((size_t)2 * 256 * 128 * 2);
    u16*   Y1      = (u16*)alloc((size_t)2 * NN * 256 * 2);
    u16*   H1      = (u16*)alloc((size_t)2 * NN * 256 * 2);
    u16*   Y2      = (u16*)alloc((size_t)2 * NN * 128 * 2);
    float* H2      = (float*)alloc((size_t)2 * NN * 128 * 4);
    u16*   R       = (u16*)alloc((size_t)NIDX * 256 * 2);
    // hist partials (25.6 MB) alias Y1 (51.2 MB): dead before Y1 is written.
    int*   partial = (int*)Y1;

    const int MT = (NN + 127) / 128;  // 391 row tiles

    // partial[enc][hist][chunk][node]; every slot written by its block -> no memset.
    hist_kernel<<<dim3(NRANGE * HCHUNK, 2), 256, 0, stream>>>(src1, dst1, src2, dst2, partial, NE);
    reduce_hist_kernel<<<(4 * NN + 255) / 256, 256, 0, stream>>>(partial, deg_all);
    norm_kernel<<<(4 * NN + 255) / 256, 256, 0, stream>>>(deg_all, norms, 4 * NN);
    scan_kernel<<<2, 1024, 0, stream>>>(deg_all, rp_all, cur_all, NN);
    // 2E/1024 chunks x 8 ranges, range = blockIdx%8 -> XCD-local csr writes
    scatter_kernel<<<(2 * NE / 1024) * NRANGE, 256, 0, stream>>>(
        src1, dst1, src2, dst2, cur_all, csr_all, NE);
    convw_kernel<<<dim3((512 * 256 + 255) / 256, 4), 256, 0, stream>>>(W1[0], W1[1], W2[0], W2[1], W1t, W2t);

    // Y1 = (raw @ W1) * ns[row]   (both encoders; f32 A converted on the fly)
    gemm_kernel<true, true, false, true><<<dim3(MT, 2, 2), 256, 0, stream>>>(
        raw[0], raw[1], W1t, W1t + (size_t)512 * 256, Y1, Y1 + (size_t)NN * 256,
        norms, norms + (size_t)2 * NN, NN, 256, 512);
    // H1 = relu(nd * agg(Y1) + b1), bf16
    agg_kernel<256, true, true><<<dim3((NN + 3) / 4, 2), 256, 0, stream>>>(
        Y1, rp_all, csr_all, norms, b1[0], b1[1], H1, NN);
    // Y2 = (H1 @ W2) * ns[row]
    gemm_kernel<false, true, false, true><<<dim3(MT, 1, 2), 256, 0, stream>>>(
        H1, H1 + (size_t)NN * 256, W2t, W2t + (size_t)256 * 128, Y2, Y2 + (size_t)NN * 128,
        norms, norms + (size_t)2 * NN, NN, 128, 256);
    // H2 = nd * agg(Y2) + b2, f32
    agg_kernel<128, false, false><<<dim3((NN + 3) / 4, 2), 256, 0, stream>>>(
        Y2, rp_all, csr_all, norms, b2[0], b2[1], H2, NN);

    // R = [ (c1n+c2n)/2 , (c1n-c2n)/(2*sqrt(3)) ]  (8192 x 256, bf16)
    build_r_kernel<<<NIDX / 4, 256, 0, stream>>>(H2, H2 + (size_t)NN * 128, index, R);
    // z = triu(R @ R^T), nontemporal f32 output
    gemm_kernel<false, false, true, false><<<dim3(64, 64, 1), 256, 0, stream>>>(
        R, R, R, R, (float*)d_out, (float*)d_out, nullptr, nullptr, NIDX, NIDX, 256);
}